// Round 9
// baseline (139.815 us; speedup 1.0000x reference)
//
#include <hip/hip_runtime.h>
#include <hip/hip_bf16.h>

// out = exp(Q K^T) V, unnormalized. B=4, S=4096, D=64, fp32 in/out.
// Round 15: BQ=256 via 16-wave blocks -- halves kf/vf re-read demand.
// R14 counters (attn_main6 warm): 66.7us, MfmaUtil 9.7%, VALU 15.3%,
// FETCH 66MB vs ~8MB unique, hbm 2.5TB/s -> the loop is SUPPLY-bound on
// kf/vf re-reads (demand = (S/BQ) passes x 4MB = 128MB at BQ=128; kh-split
// does NOT change it -- R14's real lesson). Fix: BQ=256 -> 16 passes=64MB.
//  * 1024 thr/block = 16 waves (4 mh x 4 kkq); per-wave code and register
//    footprint IDENTICAL to the verified R6 wave (2 mt, oacc[2][2], ~88
//    VGPR <= 128 cap at launch_bounds(1024,4)).
//  * grid 256 = 16 q-blocks x 16 (b,kh-qtr) slices; slice = bid&15 pins
//    each 256KB slice to an XCD under %8 round-robin -> L2-resident
//    re-reads. 64KB double-buffer, R6-verified vmcnt(0)+1-barrier loop,
//    2 DMA chunks per wave per tile.
//  * Epilogue: 4-round LDS reduce (dt x mh-pair, 48KB scratch) -> disjoint
//    partial[4] streaming stores -> reduce_out4 (R14-verified path).

typedef short    s16x4 __attribute__((ext_vector_type(4)));
typedef short    s16x8 __attribute__((ext_vector_type(8)));
typedef _Float16 h16x8 __attribute__((ext_vector_type(8)));
typedef float    fx4   __attribute__((ext_vector_type(4)));
typedef float    fx16  __attribute__((ext_vector_type(16)));

constexpr int S = 4096, D = 64, BN = 128;
constexpr int QROWS = 256;                          // q-rows per block (16 waves)
constexpr int TILES = S / BN;                       // 32
constexpr int QTR_TILES = TILES / 4;                // 8 per kk-quarter
constexpr int TILE_SHORTS  = 16 * 512;              // 16KB per array per tile
constexpr int BATCH_SHORTS = TILES * TILE_SHORTS;   // 262144

__device__ __forceinline__ unsigned short f2bf(float x) {
    unsigned u = __float_as_uint(x);
    u = (u + 0x7FFFu + ((u >> 16) & 1u)) >> 16;   // RNE
    return (unsigned short)u;
}
__device__ __forceinline__ float bf2f(unsigned short h) {
    return __uint_as_float(((unsigned)h) << 16);
}
__device__ __forceinline__ unsigned short f2h(float x) {
    union { _Float16 h; unsigned short s; } u;
    u.h = (_Float16)x;
    return u.s;
}
__device__ __forceinline__ unsigned pack_bf16(float lo, float hi) {
    __hip_bfloat162 r = __float22bfloat162_rn(make_float2(lo, hi));
    union { __hip_bfloat162 b; unsigned u; } c;
    c.b = r;
    return c.u;
}
__device__ __forceinline__ float ex2(float x) {
#if __has_builtin(__builtin_amdgcn_exp2f)
    return __builtin_amdgcn_exp2f(x);
#else
    return exp2f(x);
#endif
}

// -------- prep: K -> fp16 A-frag order, V -> bf16 B-frag order (32x32x16) ---
// K chunk c = kkq*4+ks : [lane][j] = K[t*128 + kkq*32 + (lane&31)][ks*16 + (lane>>5)*8 + j]
// V chunk c = ss*2+dt  : [lane][j] = V[t*128 + ss*16 + (lane>>5)*8 + j][dt*32 + (lane&31)]
__global__ __launch_bounds__(256) void prep2(
    const float* __restrict__ k, const float* __restrict__ v,
    unsigned short* __restrict__ kf, unsigned short* __restrict__ vf)
{
    __shared__ unsigned short tile[128 * 72];   // row stride 72 halves (pad)
    const int tid   = threadIdx.x;
    const int which = blockIdx.x & 1;           // 0 = K, 1 = V
    const int t     = (blockIdx.x >> 1) & 31;
    const int b     = blockIdx.x >> 6;
    const float* src = (which ? v : k) + ((size_t)b * S + t * BN) * D;

    #pragma unroll
    for (int i = 0; i < 8; ++i) {               // coalesced: 2048 float4s/block
        int f   = i * 256 + tid;
        int row = f >> 4;
        int c4  = (f & 15) << 2;
        float4 x = *(const float4*)(src + row * D + c4);
        s16x4 o;
        if (which) o = (s16x4){(short)f2bf(x.x), (short)f2bf(x.y),
                               (short)f2bf(x.z), (short)f2bf(x.w)};
        else       o = (s16x4){(short)f2h(x.x), (short)f2h(x.y),
                               (short)f2h(x.z), (short)f2h(x.w)};
        *(s16x4*)&tile[row * 72 + c4] = o;
    }
    __syncthreads();

    const int lane = tid & 63;
    unsigned short* dst = (which ? vf : kf) + (size_t)b * BATCH_SHORTS + t * TILE_SHORTS;
    #pragma unroll
    for (int i = 0; i < 4; ++i) {
        int c = (tid >> 6) * 4 + i;             // chunk 0..15
        s16x8 o;
        if (which == 0) {
            int row = (c >> 2) * 32 + (lane & 31);
            int dc  = (c & 3) * 16 + (lane >> 5) * 8;
            o = *(const s16x8*)&tile[row * 72 + dc];     // b128, aligned
        } else {
            int r0 = (c >> 1) * 16 + (lane >> 5) * 8;
            int dc = (c & 1) * 32 + (lane & 31);
            #pragma unroll
            for (int j = 0; j < 8; ++j) o[j] = (short)tile[(r0 + j) * 72 + dc];
        }
        *(s16x8*)(dst + c * 512 + lane * 8) = o;         // coalesced b128
    }
}

// ------------- main: 256 q-rows, one kk-QUARTER (8 tiles) per block --------
// 256 blocks x 1024 thr (16 waves = 4 mh x 4 kkq). Per-wave code identical
// to the verified R6 wave. Streaming partial stores, reduced by reduce_out4.
__global__ __launch_bounds__(1024, 4) void attn_main7(
    const float* __restrict__ q, const unsigned short* __restrict__ kf,
    const unsigned short* __restrict__ vf, float* __restrict__ partial)
{
    __shared__ unsigned short smem[2 * 2 * TILE_SHORTS];   // 64KB: 2 x (K|V)

    const int tid = threadIdx.x, lane = tid & 63, w = tid >> 6;   // w 0..15
    const int h = lane >> 5, m5 = lane & 31;
    const int mh = w & 3, kkq = w >> 2;         // m-quarter (64 rows), kk-quarter
    const int bid = blockIdx.x;
    const int slice = bid & 15;
    const int b = slice >> 2;                   // batch 0..3
    const int kh = slice & 3;                   // kk quarter-range 0..3
    const int q0 = (bid >> 4) * QROWS;
    const int t0 = kh * QTR_TILES;

    const unsigned short* kfb = kf + (size_t)b * BATCH_SHORTS;
    const unsigned short* vfb = vf + (size_t)b * BATCH_SHORTS;

    // Q B-frags fp16, pre-scaled by log2(e) so exp(s) = exp2(s').
    const float LOG2E = 1.4426950408889634f;
    h16x8 qf[2][4];   // [mt][ks]
    #pragma unroll
    for (int mt = 0; mt < 2; ++mt) {
        const float* qrow = q + ((size_t)b * S + q0 + mh * 64 + mt * 32 + m5) * D + h * 8;
        #pragma unroll
        for (int ks = 0; ks < 4; ++ks) {
            float4 a = *(const float4*)(qrow + ks * 16);
            float4 c = *(const float4*)(qrow + ks * 16 + 4);
            qf[mt][ks] = (h16x8){
                (_Float16)(a.x * LOG2E), (_Float16)(a.y * LOG2E),
                (_Float16)(a.z * LOG2E), (_Float16)(a.w * LOG2E),
                (_Float16)(c.x * LOG2E), (_Float16)(c.y * LOG2E),
                (_Float16)(c.z * LOG2E), (_Float16)(c.w * LOG2E)};
        }
    }

    fx16 oacc[2][2] = {};   // [mt][dt]

    // 2 DMAs per wave per tile: K chunk w, V chunk w (16 waves cover 0..15).
    auto issue = [&](int t, int bi) {
        unsigned short* base = &smem[bi * 2 * TILE_SHORTS];
        const unsigned short* gk = kfb + (size_t)t * TILE_SHORTS + w * 512 + lane * 8;
        unsigned short* lk = base + w * 512 + lane * 8;
        __builtin_amdgcn_global_load_lds(
            (const __attribute__((address_space(1))) unsigned int*)gk,
            (__attribute__((address_space(3))) unsigned int*)lk, 16, 0, 0);
        const unsigned short* gv = vfb + (size_t)t * TILE_SHORTS + w * 512 + lane * 8;
        unsigned short* lv = base + TILE_SHORTS + w * 512 + lane * 8;
        __builtin_amdgcn_global_load_lds(
            (const __attribute__((address_space(1))) unsigned int*)gv,
            (__attribute__((address_space(3))) unsigned int*)lv, 16, 0, 0);
    };

    issue(t0, 0);

    for (int i = 0; i < QTR_TILES; ++i) {
        const int bi = i & 1;
        // Wait own 2 DMAs of tile i (issued one phase ago); barrier proves
        // all waves' DMAs landed and buf bi^1 is fully consumed.
        __asm__ volatile("" ::: "memory");
        __builtin_amdgcn_s_waitcnt(0x0F70);   // vmcnt(0)
        __builtin_amdgcn_s_barrier();
        __asm__ volatile("" ::: "memory");
        if (i + 1 < QTR_TILES) issue(t0 + i + 1, bi ^ 1);

        const unsigned short* kb = &smem[bi * 2 * TILE_SHORTS];
        const unsigned short* vb = kb + TILE_SHORTS;

        // ---- GEMM1 (fp16 32x32x16): Sc^T[kk 32][m 32] x2 mt, d=64 ----
        fx16 sa[2] = {};
        #pragma unroll
        for (int ks = 0; ks < 4; ++ks) {
            h16x8 a = *(const h16x8*)(kb + (kkq * 4 + ks) * 512 + lane * 8);
            #pragma unroll
            for (int mt = 0; mt < 2; ++mt)
                sa[mt] = __builtin_amdgcn_mfma_f32_32x32x16_f16(a, qf[mt][ks], sa[mt], 0, 0, 0);
        }

        // ---- P = exp2(Sc^T') in regs, bf16-pair packed ----
        unsigned p01[2][8];
        #pragma unroll
        for (int mt = 0; mt < 2; ++mt)
            #pragma unroll
            for (int rp = 0; rp < 8; ++rp)
                p01[mt][rp] = pack_bf16(ex2(sa[mt][2 * rp]), ex2(sa[mt][2 * rp + 1]));

        // ---- C-layout -> GEMM2 A-layout: cross-half exchange ----
        union frag { unsigned u[4]; s16x8 v; };
        frag A[2][2];   // [mt][u]
        #pragma unroll
        for (int mt = 0; mt < 2; ++mt) {
#if __has_builtin(__builtin_amdgcn_permlane32_swap)
            typedef unsigned uix2 __attribute__((ext_vector_type(2)));
            uix2 r0 = __builtin_amdgcn_permlane32_swap(p01[mt][0], p01[mt][2], false, false);
            uix2 r1 = __builtin_amdgcn_permlane32_swap(p01[mt][1], p01[mt][3], false, false);
            A[mt][0].u[0] = r0.x; A[mt][0].u[1] = r1.x;
            A[mt][0].u[2] = r0.y; A[mt][0].u[3] = r1.y;
            uix2 r2 = __builtin_amdgcn_permlane32_swap(p01[mt][4], p01[mt][6], false, false);
            uix2 r3 = __builtin_amdgcn_permlane32_swap(p01[mt][5], p01[mt][7], false, false);
            A[mt][1].u[0] = r2.x; A[mt][1].u[1] = r3.x;
            A[mt][1].u[2] = r2.y; A[mt][1].u[3] = r3.y;
#else
            unsigned sw[8];
            #pragma unroll
            for (int rp = 0; rp < 8; ++rp)
                sw[rp] = (unsigned)__shfl_xor((int)p01[mt][rp], 32, 64);
            A[mt][0].u[0] = h ? sw[2]        : p01[mt][0];
            A[mt][0].u[1] = h ? sw[3]        : p01[mt][1];
            A[mt][0].u[2] = h ? p01[mt][2]   : sw[0];
            A[mt][0].u[3] = h ? p01[mt][3]   : sw[1];
            A[mt][1].u[0] = h ? sw[6]        : p01[mt][4];
            A[mt][1].u[1] = h ? sw[7]        : p01[mt][5];
            A[mt][1].u[2] = h ? p01[mt][6]   : sw[4];
            A[mt][1].u[3] = h ? p01[mt][7]   : sw[5];
#endif
        }

        // ---- GEMM2 (bf16 32x32x16): O += P*V over this wave's 32 kk ----
        #pragma unroll
        for (int u = 0; u < 2; ++u) {
            int ss = kkq * 2 + u;                        // 16-kk step in tile
            #pragma unroll
            for (int dt = 0; dt < 2; ++dt) {
                s16x8 vv = *(const s16x8*)(vb + (ss * 2 + dt) * 512 + lane * 8);
                #pragma unroll
                for (int mt = 0; mt < 2; ++mt)
                    oacc[mt][dt] = __builtin_amdgcn_mfma_f32_32x32x16_bf16(
                        A[mt][u].v, vv, oacc[mt][dt], 0, 0, 0);
            }
        }
    }

    // ---- epilogue: 4 rounds (dt x mh-pair), 48KB scratch each; kkq-reduce
    //      then streaming store of this block's disjoint partial region. ----
    __syncthreads();                     // all DMA drained (vmcnt(0) each iter)
    float* scratch = (float*)smem;
    float* pout = partial + ((size_t)kh * 4 + b) * S * D;
    #pragma unroll
    for (int dt = 0; dt < 2; ++dt) {
        #pragma unroll
        for (int mhg = 0; mhg < 2; ++mhg) {
            const bool act = (mh >> 1) == mhg;
            if (act && kkq > 0) {
                float* dst = scratch + (size_t)((mh & 1) * 3 + (kkq - 1)) * 2048;
                #pragma unroll
                for (int mt = 0; mt < 2; ++mt)
                    #pragma unroll
                    for (int r = 0; r < 16; ++r)
                        dst[(mt * 16 + r) * 64 + lane] = oacc[mt][dt][r];
            }
            __syncthreads();
            if (act && kkq == 0) {
                #pragma unroll
                for (int mt = 0; mt < 2; ++mt)
                    #pragma unroll
                    for (int r = 0; r < 16; ++r) {
                        float val = oacc[mt][dt][r];
                        #pragma unroll
                        for (int p = 0; p < 3; ++p)
                            val += scratch[(size_t)((mh & 1) * 3 + p) * 2048 + (mt * 16 + r) * 64 + lane];
                        int row = q0 + mh * 64 + mt * 32 + (r & 3) + 8 * (r >> 2) + 4 * h;
                        pout[(size_t)row * D + dt * 32 + m5] = val;
                    }
            }
            __syncthreads();
        }
    }
}

// ---------------- final reduce: out = p0 + p1 + p2 + p3 ----------------
__global__ __launch_bounds__(256) void reduce_out4(
    const float4* __restrict__ p0, const float4* __restrict__ p1,
    const float4* __restrict__ p2, const float4* __restrict__ p3,
    float4* __restrict__ o, int n4)
{
    int i = blockIdx.x * 256 + threadIdx.x;
    if (i < n4) {
        float4 a = p0[i], b = p1[i], c = p2[i], d = p3[i];
        o[i] = make_float4((a.x + b.x) + (c.x + d.x),
                           (a.y + b.y) + (c.y + d.y),
                           (a.z + b.z) + (c.z + d.z),
                           (a.w + b.w) + (c.w + d.w));
    }
}

// ---------------- fallback (known-good round-2 kernel) ----------------
__global__ __launch_bounds__(1024) void attn_fallback(
    const float* __restrict__ q, const float* __restrict__ k,
    const float* __restrict__ v, float* __restrict__ out)
{
    __shared__ unsigned short Kh[64][72];
    __shared__ unsigned short Kl[64][72];
    __shared__ unsigned short Vt[64][68];
    __shared__ unsigned short Pf[64][72];

    const int tid = threadIdx.x, lane = tid & 63, wave = tid >> 6;
    const int quad = lane >> 4, tq = lane & 15;
    const int kkb = wave & 3, mba = wave >> 2;
    const int b = blockIdx.y, q0 = blockIdx.x * 64;
    const float* qb = q + (size_t)b * S * D;
    const float* kb = k + (size_t)b * S * D;
    const float* vb = v + (size_t)b * S * D;
    float* ob = out + (size_t)b * S * D;

    s16x8 qh[2], ql[2];
    {
        const float* qrow = qb + (size_t)(q0 + mba * 16 + tq) * D;
        #pragma unroll
        for (int ks = 0; ks < 2; ++ks) {
            const float* src = qrow + ks * 32 + quad * 8;
            float4 f0 = *(const float4*)src;
            float4 f1 = *(const float4*)(src + 4);
            float f[8] = {f0.x, f0.y, f0.z, f0.w, f1.x, f1.y, f1.z, f1.w};
            #pragma unroll
            for (int j = 0; j < 8; ++j) {
                unsigned short hh = f2bf(f[j]);
                qh[ks][j] = (short)hh;
                ql[ks][j] = (short)f2bf(f[j] - bf2f(hh));
            }
        }
    }
    fx4 oacc = {0.f, 0.f, 0.f, 0.f};
    const int krow = tid >> 4, kc4 = (tid & 15) << 2;
    const int vd = tid & 63, vk = (tid >> 6) << 2;

    for (int t = 0; t < S / 64; ++t) {
        __syncthreads();
        const float* kt = kb + (size_t)(t * 64 + krow) * D;
        const float* vt = vb + (size_t)(t * 64 + vk) * D;
        {
            float4 kv = *(const float4*)(kt + kc4);
            unsigned short h0 = f2bf(kv.x), h1 = f2bf(kv.y), h2 = f2bf(kv.z), h3 = f2bf(kv.w);
            s16x4 a = {(short)h0, (short)h1, (short)h2, (short)h3};
            s16x4 l4 = {(short)f2bf(kv.x - bf2f(h0)), (short)f2bf(kv.y - bf2f(h1)),
                        (short)f2bf(kv.z - bf2f(h2)), (short)f2bf(kv.w - bf2f(h3))};
            *(s16x4*)&Kh[krow][kc4] = a;
            *(s16x4*)&Kl[krow][kc4] = l4;
            const float* vs = vt + vd;
            s16x4 vv = {(short)f2bf(vs[0]), (short)f2bf(vs[D]),
                        (short)f2bf(vs[2 * D]), (short)f2bf(vs[3 * D])};
            *(s16x4*)&Vt[vd][vk] = vv;
        }
        __syncthreads();
        fx4 sacc = {0.f, 0.f, 0.f, 0.f};
        #pragma unroll
        for (int ks = 0; ks < 2; ++ks) {
            s16x8 kah = *(const s16x8*)&Kh[kkb * 16 + tq][ks * 32 + quad * 8];
            s16x8 kal = *(const s16x8*)&Kl[kkb * 16 + tq][ks * 32 + quad * 8];
            sacc = __builtin_amdgcn_mfma_f32_16x16x32_bf16(kah, qh[ks], sacc, 0, 0, 0);
            sacc = __builtin_amdgcn_mfma_f32_16x16x32_bf16(kah, ql[ks], sacc, 0, 0, 0);
            sacc = __builtin_amdgcn_mfma_f32_16x16x32_bf16(kal, qh[ks], sacc, 0, 0, 0);
        }
        s16x4 pp = {(short)f2bf(__expf(sacc[0])), (short)f2bf(__expf(sacc[1])),
                    (short)f2bf(__expf(sacc[2])), (short)f2bf(__expf(sacc[3]))};
        *(s16x4*)&Pf[mba * 16 + tq][kkb * 16 + (quad << 2)] = pp;
        __syncthreads();
        #pragma unroll
        for (int ks = 0; ks < 2; ++ks) {
            s16x8 pa = *(const s16x8*)&Pf[mba * 16 + tq][ks * 32 + quad * 8];
            const unsigned short* vr = &Vt[kkb * 16 + tq][ks * 32 + quad * 8];
            s16x4 va = *(const s16x4*)vr;
            s16x4 vb2 = *(const s16x4*)(vr + 4);
            s16x8 vfull = __builtin_shufflevector(va, vb2, 0, 1, 2, 3, 4, 5, 6, 7);
            oacc = __builtin_amdgcn_mfma_f32_16x16x32_bf16(pa, vfull, oacc, 0, 0, 0);
        }
    }
    #pragma unroll
    for (int r = 0; r < 4; ++r)
        ob[(size_t)(q0 + mba * 16 + quad * 4 + r) * D + kkb * 16 + tq] = oacc[r];
}

extern "C" void kernel_launch(void* const* d_in, const int* in_sizes, int n_in,
                              void* d_out, int out_size, void* d_ws, size_t ws_size,
                              hipStream_t stream) {
    const float* q = (const float*)d_in[0];
    const float* k = (const float*)d_in[1];
    const float* v = (const float*)d_in[2];
    float* out = (float*)d_out;
    const int nbatch = in_sizes[0] / (S * D);   // 4
    const size_t elems = (size_t)nbatch * S * D;

    // ws: kf (fp16, 2MB) | vf (bf16, 2MB) | partial[4] (fp32, 16MB) = 20MB
    const size_t need = elems * 2 * 2 + elems * 4 * 4;
    if (nbatch == 4 && ws_size >= need && d_ws != nullptr) {
        unsigned short* kf = (unsigned short*)d_ws;
        unsigned short* vf = kf + elems;
        float* partial = (float*)(vf + elems);

        prep2<<<nbatch * TILES * 2, 256, 0, stream>>>(k, v, kf, vf);
        attn_main7<<<256, 1024, 0, stream>>>(q, kf, vf, partial);
        const int n4 = (int)(elems / 4);
        reduce_out4<<<(n4 + 255) / 256, 256, 0, stream>>>(
            (const float4*)partial,
            (const float4*)(partial + elems),
            (const float4*)(partial + 2 * elems),
            (const float4*)(partial + 3 * elems),
            (float4*)out, n4);
    } else {
        dim3 grid(S / 64, nbatch);
        attn_fallback<<<grid, 1024, 0, stream>>>(q, k, v, out);
    }
}

// Round 10
// 101.394 us; speedup vs baseline: 1.3789x; 1.3789x over previous
//
#include <hip/hip_runtime.h>
#include <hip/hip_bf16.h>

// out = exp(Q K^T) V, unnormalized. B=4, S=4096, D=64, fp32 in/out.
// Round 16: R14 kernel with the spill poison removed (ONE token changed).
// Cross-round forensics: launch_bounds min_waves=4 capped the allocator at
// 128 VGPR; the wave needs ~150 (oacc 64 + qf 32 + temporaries) -> the
// compiler spilled accumulators to scratch. Evidence: VGPR_Count=64 and
// WRITE_SIZE 70/98/115MB (R11/R14/R15) vs VGPR=88, WRITE=16MB for the
// (512,2) R10 kernel. Scratch reads also polluted FETCH (why R15's BQ=256
// "didn't help"). Fix: __launch_bounds__(512,2) -> 256-VGPR budget, no
// spill. Co-residency does NOT need the cap: at ~88-110 VGPR and 64KB LDS,
// two 8-wave blocks fit a CU (4x110=440<=512 VGPR/SIMD, 128KB<=160KB LDS),
// so the 512-block grid still gets 2 blocks/CU.
// Everything else identical to R14 (verified numerically): 4-way kk split,
// 64KB double-buffer, vmcnt(0)+1 barrier/iter, permlane32_swap transpose,
// exp2 prescaled-Q, disjoint partial[4] streaming stores + reduce_out4.

typedef short    s16x4 __attribute__((ext_vector_type(4)));
typedef short    s16x8 __attribute__((ext_vector_type(8)));
typedef _Float16 h16x8 __attribute__((ext_vector_type(8)));
typedef float    fx4   __attribute__((ext_vector_type(4)));
typedef float    fx16  __attribute__((ext_vector_type(16)));

constexpr int S = 4096, D = 64, BN = 128;
constexpr int QROWS = 128;                          // q-rows per block
constexpr int TILES = S / BN;                       // 32
constexpr int QTR_TILES = TILES / 4;                // 8 per kk-quarter-range
constexpr int TILE_SHORTS  = 16 * 512;              // 16KB per array per tile
constexpr int BATCH_SHORTS = TILES * TILE_SHORTS;   // 262144

__device__ __forceinline__ unsigned short f2bf(float x) {
    unsigned u = __float_as_uint(x);
    u = (u + 0x7FFFu + ((u >> 16) & 1u)) >> 16;   // RNE
    return (unsigned short)u;
}
__device__ __forceinline__ float bf2f(unsigned short h) {
    return __uint_as_float(((unsigned)h) << 16);
}
__device__ __forceinline__ unsigned short f2h(float x) {
    union { _Float16 h; unsigned short s; } u;
    u.h = (_Float16)x;
    return u.s;
}
__device__ __forceinline__ unsigned pack_bf16(float lo, float hi) {
    __hip_bfloat162 r = __float22bfloat162_rn(make_float2(lo, hi));
    union { __hip_bfloat162 b; unsigned u; } c;
    c.b = r;
    return c.u;
}
__device__ __forceinline__ float ex2(float x) {
#if __has_builtin(__builtin_amdgcn_exp2f)
    return __builtin_amdgcn_exp2f(x);
#else
    return exp2f(x);
#endif
}

// -------- prep: K -> fp16 A-frag order, V -> bf16 B-frag order (32x32x16) ---
// K chunk c = kkq*4+ks : [lane][j] = K[t*128 + kkq*32 + (lane&31)][ks*16 + (lane>>5)*8 + j]
// V chunk c = ss*2+dt  : [lane][j] = V[t*128 + ss*16 + (lane>>5)*8 + j][dt*32 + (lane&31)]
__global__ __launch_bounds__(256) void prep2(
    const float* __restrict__ k, const float* __restrict__ v,
    unsigned short* __restrict__ kf, unsigned short* __restrict__ vf)
{
    __shared__ unsigned short tile[128 * 72];   // row stride 72 halves (pad)
    const int tid   = threadIdx.x;
    const int which = blockIdx.x & 1;           // 0 = K, 1 = V
    const int t     = (blockIdx.x >> 1) & 31;
    const int b     = blockIdx.x >> 6;
    const float* src = (which ? v : k) + ((size_t)b * S + t * BN) * D;

    #pragma unroll
    for (int i = 0; i < 8; ++i) {               // coalesced: 2048 float4s/block
        int f   = i * 256 + tid;
        int row = f >> 4;
        int c4  = (f & 15) << 2;
        float4 x = *(const float4*)(src + row * D + c4);
        s16x4 o;
        if (which) o = (s16x4){(short)f2bf(x.x), (short)f2bf(x.y),
                               (short)f2bf(x.z), (short)f2bf(x.w)};
        else       o = (s16x4){(short)f2h(x.x), (short)f2h(x.y),
                               (short)f2h(x.z), (short)f2h(x.w)};
        *(s16x4*)&tile[row * 72 + c4] = o;
    }
    __syncthreads();

    const int lane = tid & 63;
    unsigned short* dst = (which ? vf : kf) + (size_t)b * BATCH_SHORTS + t * TILE_SHORTS;
    #pragma unroll
    for (int i = 0; i < 4; ++i) {
        int c = (tid >> 6) * 4 + i;             // chunk 0..15
        s16x8 o;
        if (which == 0) {
            int row = (c >> 2) * 32 + (lane & 31);
            int dc  = (c & 3) * 16 + (lane >> 5) * 8;
            o = *(const s16x8*)&tile[row * 72 + dc];     // b128, aligned
        } else {
            int r0 = (c >> 1) * 16 + (lane >> 5) * 8;
            int dc = (c & 1) * 32 + (lane & 31);
            #pragma unroll
            for (int j = 0; j < 8; ++j) o[j] = (short)tile[(r0 + j) * 72 + dc];
        }
        *(s16x8*)(dst + c * 512 + lane * 8) = o;         // coalesced b128
    }
}

// ---------------- main: 128 q-rows, one kk-QUARTER (8 tiles) per block -----
// 512 blocks; at ~88-110 VGPR + 64KB LDS the HW places 2 blocks/CU.
// bid&15 = (b,kh) slice; same-slice q-blocks share a 512KB kf/vf working
// set (L2-resident). Streaming partial stores, reduced by reduce_out4.
__global__ __launch_bounds__(512, 2) void attn_main6(
    const float* __restrict__ q, const unsigned short* __restrict__ kf,
    const unsigned short* __restrict__ vf, float* __restrict__ partial)
{
    __shared__ unsigned short smem[2 * 2 * TILE_SHORTS];   // 64KB: 2 x (K|V)

    const int tid = threadIdx.x, lane = tid & 63, w = tid >> 6;
    const int h = lane >> 5, m5 = lane & 31;
    const int mh = w & 1, kkq = w >> 1;         // m-half (64 rows), kk-quarter
    const int bid = blockIdx.x;
    const int slice = bid & 15;
    const int b = slice >> 2;                   // batch 0..3
    const int kh = slice & 3;                   // kk quarter-range 0..3
    const int q0 = (bid >> 4) * QROWS;
    const int t0 = kh * QTR_TILES;

    const unsigned short* kfb = kf + (size_t)b * BATCH_SHORTS;
    const unsigned short* vfb = vf + (size_t)b * BATCH_SHORTS;

    // Q B-frags fp16, pre-scaled by log2(e) so exp(s) = exp2(s').
    const float LOG2E = 1.4426950408889634f;
    h16x8 qf[2][4];   // [mt][ks]
    #pragma unroll
    for (int mt = 0; mt < 2; ++mt) {
        const float* qrow = q + ((size_t)b * S + q0 + mh * 64 + mt * 32 + m5) * D + h * 8;
        #pragma unroll
        for (int ks = 0; ks < 4; ++ks) {
            float4 a = *(const float4*)(qrow + ks * 16);
            float4 c = *(const float4*)(qrow + ks * 16 + 4);
            qf[mt][ks] = (h16x8){
                (_Float16)(a.x * LOG2E), (_Float16)(a.y * LOG2E),
                (_Float16)(a.z * LOG2E), (_Float16)(a.w * LOG2E),
                (_Float16)(c.x * LOG2E), (_Float16)(c.y * LOG2E),
                (_Float16)(c.z * LOG2E), (_Float16)(c.w * LOG2E)};
        }
    }

    fx16 oacc[2][2] = {};   // [mt][dt]

    auto issue = [&](int t, int bi) {
        unsigned short* base = &smem[bi * 2 * TILE_SHORTS];
        #pragma unroll
        for (int ii = 0; ii < 4; ++ii) {                 // ii<2: K, else V
            int c = (ii & 1) * 8 + w;                    // chunk 0..15
            const unsigned short* g = (ii < 2 ? kfb : vfb)
                + (size_t)t * TILE_SHORTS + c * 512 + lane * 8;
            unsigned short* l = base + (ii < 2 ? 0 : TILE_SHORTS) + c * 512 + lane * 8;
            __builtin_amdgcn_global_load_lds(
                (const __attribute__((address_space(1))) unsigned int*)g,
                (__attribute__((address_space(3))) unsigned int*)l, 16, 0, 0);
        }
    };

    issue(t0, 0);

    for (int i = 0; i < QTR_TILES; ++i) {
        const int bi = i & 1;
        // Wait own 4 DMAs of tile i (issued one phase ago); barrier proves
        // all waves done reading buf bi^1 -> safe to refill it.
        __asm__ volatile("" ::: "memory");
        __builtin_amdgcn_s_waitcnt(0x0F70);   // vmcnt(0)
        __builtin_amdgcn_s_barrier();
        __asm__ volatile("" ::: "memory");
        if (i + 1 < QTR_TILES) issue(t0 + i + 1, bi ^ 1);

        const unsigned short* kb = &smem[bi * 2 * TILE_SHORTS];
        const unsigned short* vb = kb + TILE_SHORTS;

        // ---- GEMM1 (fp16 32x32x16): Sc^T[kk 32][m 32] x2 mt, d=64 ----
        fx16 sa[2] = {};
        #pragma unroll
        for (int ks = 0; ks < 4; ++ks) {
            h16x8 a = *(const h16x8*)(kb + (kkq * 4 + ks) * 512 + lane * 8);
            #pragma unroll
            for (int mt = 0; mt < 2; ++mt)
                sa[mt] = __builtin_amdgcn_mfma_f32_32x32x16_f16(a, qf[mt][ks], sa[mt], 0, 0, 0);
        }

        // ---- P = exp2(Sc^T') in regs, bf16-pair packed ----
        unsigned p01[2][8];
        #pragma unroll
        for (int mt = 0; mt < 2; ++mt)
            #pragma unroll
            for (int rp = 0; rp < 8; ++rp)
                p01[mt][rp] = pack_bf16(ex2(sa[mt][2 * rp]), ex2(sa[mt][2 * rp + 1]));

        // ---- C-layout -> GEMM2 A-layout: cross-half exchange ----
        union frag { unsigned u[4]; s16x8 v; };
        frag A[2][2];   // [mt][u]
        #pragma unroll
        for (int mt = 0; mt < 2; ++mt) {
#if __has_builtin(__builtin_amdgcn_permlane32_swap)
            typedef unsigned uix2 __attribute__((ext_vector_type(2)));
            uix2 r0 = __builtin_amdgcn_permlane32_swap(p01[mt][0], p01[mt][2], false, false);
            uix2 r1 = __builtin_amdgcn_permlane32_swap(p01[mt][1], p01[mt][3], false, false);
            A[mt][0].u[0] = r0.x; A[mt][0].u[1] = r1.x;
            A[mt][0].u[2] = r0.y; A[mt][0].u[3] = r1.y;
            uix2 r2 = __builtin_amdgcn_permlane32_swap(p01[mt][4], p01[mt][6], false, false);
            uix2 r3 = __builtin_amdgcn_permlane32_swap(p01[mt][5], p01[mt][7], false, false);
            A[mt][1].u[0] = r2.x; A[mt][1].u[1] = r3.x;
            A[mt][1].u[2] = r2.y; A[mt][1].u[3] = r3.y;
#else
            unsigned sw[8];
            #pragma unroll
            for (int rp = 0; rp < 8; ++rp)
                sw[rp] = (unsigned)__shfl_xor((int)p01[mt][rp], 32, 64);
            A[mt][0].u[0] = h ? sw[2]        : p01[mt][0];
            A[mt][0].u[1] = h ? sw[3]        : p01[mt][1];
            A[mt][0].u[2] = h ? p01[mt][2]   : sw[0];
            A[mt][0].u[3] = h ? p01[mt][3]   : sw[1];
            A[mt][1].u[0] = h ? sw[6]        : p01[mt][4];
            A[mt][1].u[1] = h ? sw[7]        : p01[mt][5];
            A[mt][1].u[2] = h ? p01[mt][6]   : sw[4];
            A[mt][1].u[3] = h ? p01[mt][7]   : sw[5];
#endif
        }

        // ---- GEMM2 (bf16 32x32x16): O += P*V over this wave's 32 kk ----
        #pragma unroll
        for (int u = 0; u < 2; ++u) {
            int ss = kkq * 2 + u;                        // 16-kk step in tile
            #pragma unroll
            for (int dt = 0; dt < 2; ++dt) {
                s16x8 vv = *(const s16x8*)(vb + (ss * 2 + dt) * 512 + lane * 8);
                #pragma unroll
                for (int mt = 0; mt < 2; ++mt)
                    oacc[mt][dt] = __builtin_amdgcn_mfma_f32_32x32x16_bf16(
                        A[mt][u].v, vv, oacc[mt][dt], 0, 0, 0);
            }
        }
    }

    // ---- epilogue: LDS-reduce 4 kk-quarter waves, then streaming store of
    //      this block's partial (disjoint region per (kh,b,q0)). ----
    __syncthreads();                     // all DMA drained (vmcnt(0) each iter)
    float* scratch = (float*)smem;
    float* pout = partial + ((size_t)kh * 4 + b) * S * D;
    #pragma unroll
    for (int dt = 0; dt < 2; ++dt) {
        if (kkq > 0) {
            float* dst = scratch + (size_t)(mh * 3 + (kkq - 1)) * 2048;
            #pragma unroll
            for (int mt = 0; mt < 2; ++mt)
                #pragma unroll
                for (int r = 0; r < 16; ++r)
                    dst[(mt * 16 + r) * 64 + lane] = oacc[mt][dt][r];
        }
        __syncthreads();
        if (kkq == 0) {
            #pragma unroll
            for (int mt = 0; mt < 2; ++mt)
                #pragma unroll
                for (int r = 0; r < 16; ++r) {
                    float val = oacc[mt][dt][r];
                    #pragma unroll
                    for (int p = 0; p < 3; ++p)
                        val += scratch[(size_t)(mh * 3 + p) * 2048 + (mt * 16 + r) * 64 + lane];
                    int row = q0 + mh * 64 + mt * 32 + (r & 3) + 8 * (r >> 2) + 4 * h;
                    pout[(size_t)row * D + dt * 32 + m5] = val;
                }
        }
        __syncthreads();
    }
}

// ---------------- final reduce: out = p0 + p1 + p2 + p3 ----------------
__global__ __launch_bounds__(256) void reduce_out4(
    const float4* __restrict__ p0, const float4* __restrict__ p1,
    const float4* __restrict__ p2, const float4* __restrict__ p3,
    float4* __restrict__ o, int n4)
{
    int i = blockIdx.x * 256 + threadIdx.x;
    if (i < n4) {
        float4 a = p0[i], b = p1[i], c = p2[i], d = p3[i];
        o[i] = make_float4((a.x + b.x) + (c.x + d.x),
                           (a.y + b.y) + (c.y + d.y),
                           (a.z + b.z) + (c.z + d.z),
                           (a.w + b.w) + (c.w + d.w));
    }
}

// ---------------- fallback (known-good round-2 kernel) ----------------
__global__ __launch_bounds__(1024) void attn_fallback(
    const float* __restrict__ q, const float* __restrict__ k,
    const float* __restrict__ v, float* __restrict__ out)
{
    __shared__ unsigned short Kh[64][72];
    __shared__ unsigned short Kl[64][72];
    __shared__ unsigned short Vt[64][68];
    __shared__ unsigned short Pf[64][72];

    const int tid = threadIdx.x, lane = tid & 63, wave = tid >> 6;
    const int quad = lane >> 4, tq = lane & 15;
    const int kkb = wave & 3, mba = wave >> 2;
    const int b = blockIdx.y, q0 = blockIdx.x * 64;
    const float* qb = q + (size_t)b * S * D;
    const float* kb = k + (size_t)b * S * D;
    const float* vb = v + (size_t)b * S * D;
    float* ob = out + (size_t)b * S * D;

    s16x8 qh[2], ql[2];
    {
        const float* qrow = qb + (size_t)(q0 + mba * 16 + tq) * D;
        #pragma unroll
        for (int ks = 0; ks < 2; ++ks) {
            const float* src = qrow + ks * 32 + quad * 8;
            float4 f0 = *(const float4*)src;
            float4 f1 = *(const float4*)(src + 4);
            float f[8] = {f0.x, f0.y, f0.z, f0.w, f1.x, f1.y, f1.z, f1.w};
            #pragma unroll
            for (int j = 0; j < 8; ++j) {
                unsigned short hh = f2bf(f[j]);
                qh[ks][j] = (short)hh;
                ql[ks][j] = (short)f2bf(f[j] - bf2f(hh));
            }
        }
    }
    fx4 oacc = {0.f, 0.f, 0.f, 0.f};
    const int krow = tid >> 4, kc4 = (tid & 15) << 2;
    const int vd = tid & 63, vk = (tid >> 6) << 2;

    for (int t = 0; t < S / 64; ++t) {
        __syncthreads();
        const float* kt = kb + (size_t)(t * 64 + krow) * D;
        const float* vt = vb + (size_t)(t * 64 + vk) * D;
        {
            float4 kv = *(const float4*)(kt + kc4);
            unsigned short h0 = f2bf(kv.x), h1 = f2bf(kv.y), h2 = f2bf(kv.z), h3 = f2bf(kv.w);
            s16x4 a = {(short)h0, (short)h1, (short)h2, (short)h3};
            s16x4 l4 = {(short)f2bf(kv.x - bf2f(h0)), (short)f2bf(kv.y - bf2f(h1)),
                        (short)f2bf(kv.z - bf2f(h2)), (short)f2bf(kv.w - bf2f(h3))};
            *(s16x4*)&Kh[krow][kc4] = a;
            *(s16x4*)&Kl[krow][kc4] = l4;
            const float* vs = vt + vd;
            s16x4 vv = {(short)f2bf(vs[0]), (short)f2bf(vs[D]),
                        (short)f2bf(vs[2 * D]), (short)f2bf(vs[3 * D])};
            *(s16x4*)&Vt[vd][vk] = vv;
        }
        __syncthreads();
        fx4 sacc = {0.f, 0.f, 0.f, 0.f};
        #pragma unroll
        for (int ks = 0; ks < 2; ++ks) {
            s16x8 kah = *(const s16x8*)&Kh[kkb * 16 + tq][ks * 32 + quad * 8];
            s16x8 kal = *(const s16x8*)&Kl[kkb * 16 + tq][ks * 32 + quad * 8];
            sacc = __builtin_amdgcn_mfma_f32_16x16x32_bf16(kah, qh[ks], sacc, 0, 0, 0);
            sacc = __builtin_amdgcn_mfma_f32_16x16x32_bf16(kah, ql[ks], sacc, 0, 0, 0);
            sacc = __builtin_amdgcn_mfma_f32_16x16x32_bf16(kal, qh[ks], sacc, 0, 0, 0);
        }
        s16x4 pp = {(short)f2bf(__expf(sacc[0])), (short)f2bf(__expf(sacc[1])),
                    (short)f2bf(__expf(sacc[2])), (short)f2bf(__expf(sacc[3]))};
        *(s16x4*)&Pf[mba * 16 + tq][kkb * 16 + (quad << 2)] = pp;
        __syncthreads();
        #pragma unroll
        for (int ks = 0; ks < 2; ++ks) {
            s16x8 pa = *(const s16x8*)&Pf[mba * 16 + tq][ks * 32 + quad * 8];
            const unsigned short* vr = &Vt[kkb * 16 + tq][ks * 32 + quad * 8];
            s16x4 va = *(const s16x4*)vr;
            s16x4 vb2 = *(const s16x4*)(vr + 4);
            s16x8 vfull = __builtin_shufflevector(va, vb2, 0, 1, 2, 3, 4, 5, 6, 7);
            oacc = __builtin_amdgcn_mfma_f32_16x16x32_bf16(pa, vfull, oacc, 0, 0, 0);
        }
    }
    #pragma unroll
    for (int r = 0; r < 4; ++r)
        ob[(size_t)(q0 + mba * 16 + quad * 4 + r) * D + kkb * 16 + tq] = oacc[r];
}

extern "C" void kernel_launch(void* const* d_in, const int* in_sizes, int n_in,
                              void* d_out, int out_size, void* d_ws, size_t ws_size,
                              hipStream_t stream) {
    const float* q = (const float*)d_in[0];
    const float* k = (const float*)d_in[1];
    const float* v = (const float*)d_in[2];
    float* out = (float*)d_out;
    const int nbatch = in_sizes[0] / (S * D);   // 4
    const size_t elems = (size_t)nbatch * S * D;

    // ws: kf (fp16, 2MB) | vf (bf16, 2MB) | partial[4] (fp32, 16MB) = 20MB
    const size_t need = elems * 2 * 2 + elems * 4 * 4;
    if (nbatch == 4 && ws_size >= need && d_ws != nullptr) {
        unsigned short* kf = (unsigned short*)d_ws;
        unsigned short* vf = kf + elems;
        float* partial = (float*)(vf + elems);

        prep2<<<nbatch * TILES * 2, 256, 0, stream>>>(k, v, kf, vf);
        attn_main6<<<512, 512, 0, stream>>>(q, kf, vf, partial);
        const int n4 = (int)(elems / 4);
        reduce_out4<<<(n4 + 255) / 256, 256, 0, stream>>>(
            (const float4*)partial,
            (const float4*)(partial + elems),
            (const float4*)(partial + 2 * elems),
            (const float4*)(partial + 3 * elems),
            (float4*)out, n4);
    } else {
        dim3 grid(S / 64, nbatch);
        attn_fallback<<<grid, 1024, 0, stream>>>(q, k, v, out);
    }
}

// Round 11
// 99.693 us; speedup vs baseline: 1.4025x; 1.0171x over previous
//
#include <hip/hip_runtime.h>
#include <hip/hip_bf16.h>

// out = exp(Q K^T) V, unnormalized. B=4, S=4096, D=64, fp32 in/out.
// Round 17: BARRIER-FREE 1-wave blocks.
// Cross-round invariant: ~2.2-3.2us per barrier'd tile-iteration in EVERY
// variant (R6/R10/R16), vs ~800 cyc of pipe work -> the 8-wave lockstep
// convoy (barrier + vmcnt drain, 1 block/CU) is the stall, not DMA depth.
// Chunk algebra: each wave consumes EXACTLY the 8KB it DMAs (K chunks
// kkq*4+ks == V chunks kkq*4+u*2+dt). So: 64-thread blocks, one wave each,
// private 16KB LDS dbuf, own vmcnt pacing, ZERO barriers. 2048 blocks
// (64 qb x 4 b x 2 kh x 4 kkq) = 8 independent waves/CU (128KB LDS);
// waves drift -> DMA latency hides under other waves' compute.
// Epilogue: direct reg->partial store (wave owns full d=64 for its rows,
// no LDS reduce); partial[8] summed by reduce_out8 (streaming, no RMW).
// R16 confirmed clean: VGPR 80 no-spill, WRITE=payload, FETCH L2-resident.

typedef short    s16x4 __attribute__((ext_vector_type(4)));
typedef short    s16x8 __attribute__((ext_vector_type(8)));
typedef _Float16 h16x8 __attribute__((ext_vector_type(8)));
typedef float    fx4   __attribute__((ext_vector_type(4)));
typedef float    fx16  __attribute__((ext_vector_type(16)));

constexpr int S = 4096, D = 64, BN = 128;
constexpr int TILES = S / BN;                       // 32
constexpr int HALF_TILES = TILES / 2;               // 16 per kk-half
constexpr int TILE_SHORTS  = 16 * 512;              // 16KB per array per tile
constexpr int BATCH_SHORTS = TILES * TILE_SHORTS;   // 262144

__device__ __forceinline__ unsigned short f2bf(float x) {
    unsigned u = __float_as_uint(x);
    u = (u + 0x7FFFu + ((u >> 16) & 1u)) >> 16;   // RNE
    return (unsigned short)u;
}
__device__ __forceinline__ float bf2f(unsigned short h) {
    return __uint_as_float(((unsigned)h) << 16);
}
__device__ __forceinline__ unsigned short f2h(float x) {
    union { _Float16 h; unsigned short s; } u;
    u.h = (_Float16)x;
    return u.s;
}
__device__ __forceinline__ unsigned pack_bf16(float lo, float hi) {
    __hip_bfloat162 r = __float22bfloat162_rn(make_float2(lo, hi));
    union { __hip_bfloat162 b; unsigned u; } c;
    c.b = r;
    return c.u;
}
__device__ __forceinline__ float ex2(float x) {
#if __has_builtin(__builtin_amdgcn_exp2f)
    return __builtin_amdgcn_exp2f(x);
#else
    return exp2f(x);
#endif
}

// -------- prep: K -> fp16 A-frag order, V -> bf16 B-frag order (32x32x16) ---
// K chunk c = kkq*4+ks : [lane][j] = K[t*128 + kkq*32 + (lane&31)][ks*16 + (lane>>5)*8 + j]
// V chunk c = ss*2+dt  : [lane][j] = V[t*128 + ss*16 + (lane>>5)*8 + j][dt*32 + (lane&31)]
__global__ __launch_bounds__(256) void prep2(
    const float* __restrict__ k, const float* __restrict__ v,
    unsigned short* __restrict__ kf, unsigned short* __restrict__ vf)
{
    __shared__ unsigned short tile[128 * 72];   // row stride 72 halves (pad)
    const int tid   = threadIdx.x;
    const int which = blockIdx.x & 1;           // 0 = K, 1 = V
    const int t     = (blockIdx.x >> 1) & 31;
    const int b     = blockIdx.x >> 6;
    const float* src = (which ? v : k) + ((size_t)b * S + t * BN) * D;

    #pragma unroll
    for (int i = 0; i < 8; ++i) {               // coalesced: 2048 float4s/block
        int f   = i * 256 + tid;
        int row = f >> 4;
        int c4  = (f & 15) << 2;
        float4 x = *(const float4*)(src + row * D + c4);
        s16x4 o;
        if (which) o = (s16x4){(short)f2bf(x.x), (short)f2bf(x.y),
                               (short)f2bf(x.z), (short)f2bf(x.w)};
        else       o = (s16x4){(short)f2h(x.x), (short)f2h(x.y),
                               (short)f2h(x.z), (short)f2h(x.w)};
        *(s16x4*)&tile[row * 72 + c4] = o;
    }
    __syncthreads();

    const int lane = tid & 63;
    unsigned short* dst = (which ? vf : kf) + (size_t)b * BATCH_SHORTS + t * TILE_SHORTS;
    #pragma unroll
    for (int i = 0; i < 4; ++i) {
        int c = (tid >> 6) * 4 + i;             // chunk 0..15
        s16x8 o;
        if (which == 0) {
            int row = (c >> 2) * 32 + (lane & 31);
            int dc  = (c & 3) * 16 + (lane >> 5) * 8;
            o = *(const s16x8*)&tile[row * 72 + dc];     // b128, aligned
        } else {
            int r0 = (c >> 1) * 16 + (lane >> 5) * 8;
            int dc = (c & 1) * 32 + (lane & 31);
            #pragma unroll
            for (int j = 0; j < 8; ++j) o[j] = (short)tile[(r0 + j) * 72 + dc];
        }
        *(s16x8*)(dst + c * 512 + lane * 8) = o;         // coalesced b128
    }
}

// -------- main: ONE WAVE per block, 64 q-rows x one (kh,kkq) kk slice -----
// 2048 blocks x 64 thr. Private 16KB LDS double-buffer; the wave consumes
// exactly what it DMAs -> no barriers anywhere. bid&7 = (b,kh) slice
// (XCD-pinned under %8 round-robin; 512KB/slice L2-resident).
__global__ __launch_bounds__(64) void attn_main8(
    const float* __restrict__ q, const unsigned short* __restrict__ kf,
    const unsigned short* __restrict__ vf, float* __restrict__ partial)
{
    __shared__ unsigned short smem[2 * 8 * 512];   // 16KB: 2 bufs x 8KB

    const int lane = threadIdx.x;               // 0..63 (one wave)
    const int h = lane >> 5, m5 = lane & 31;
    const int bid = blockIdx.x;
    const int slice = bid & 7;                  // -> XCD pin
    const int b = slice >> 1;                   // batch 0..3
    const int kh = slice & 1;                   // kk-half 0/1
    const int idx = bid >> 3;                   // 0..255 = qb*4 + kkq
    const int kkq = idx & 3;                    // kk-quarter within tile
    const int q0 = (idx >> 2) * 64;             // 64 q-rows per wave
    const int t0 = kh * HALF_TILES;

    const unsigned short* kfb = kf + (size_t)b * BATCH_SHORTS;
    const unsigned short* vfb = vf + (size_t)b * BATCH_SHORTS;

    // Q B-frags fp16, pre-scaled by log2(e) so exp(s) = exp2(s').
    const float LOG2E = 1.4426950408889634f;
    h16x8 qf[2][4];   // [mt][ks]
    #pragma unroll
    for (int mt = 0; mt < 2; ++mt) {
        const float* qrow = q + ((size_t)b * S + q0 + mt * 32 + m5) * D + h * 8;
        #pragma unroll
        for (int ks = 0; ks < 4; ++ks) {
            float4 a = *(const float4*)(qrow + ks * 16);
            float4 c = *(const float4*)(qrow + ks * 16 + 4);
            qf[mt][ks] = (h16x8){
                (_Float16)(a.x * LOG2E), (_Float16)(a.y * LOG2E),
                (_Float16)(a.z * LOG2E), (_Float16)(a.w * LOG2E),
                (_Float16)(c.x * LOG2E), (_Float16)(c.y * LOG2E),
                (_Float16)(c.z * LOG2E), (_Float16)(c.w * LOG2E)};
        }
    }

    fx16 oacc[2][2] = {};   // [mt][dt]

    // 8 x 1KB DMAs per tile: local ii<4 = K chunks kkq*4+ii,
    // ii>=4 = V chunks kkq*4+(ii-4). Issue order K,K,K,K,V,V,V,V.
    auto issue = [&](int t, int bi) {
        unsigned short* base = &smem[bi * 8 * 512];
        #pragma unroll
        for (int ii = 0; ii < 8; ++ii) {
            int c = kkq * 4 + (ii & 3);
            const unsigned short* g = (ii < 4 ? kfb : vfb)
                + (size_t)t * TILE_SHORTS + c * 512 + lane * 8;
            unsigned short* l = base + ii * 512 + lane * 8;
            __builtin_amdgcn_global_load_lds(
                (const __attribute__((address_space(1))) unsigned int*)g,
                (__attribute__((address_space(3))) unsigned int*)l, 16, 0, 0);
        }
    };

    issue(t0 + 0, 0);
    issue(t0 + 1, 1);

    for (int i = 0; i < HALF_TILES; ++i) {
        const int bi = i & 1;
        // Own-wave pacing only: vmcnt(8) retires the oldest 8 = tile i's
        // loads (8 newer = tile i+1's). No barrier -- nobody else reads
        // this LDS. Last iter: nothing newer in flight -> vmcnt(0).
        __asm__ volatile("" ::: "memory");
        if (i + 1 < HALF_TILES) {
            __builtin_amdgcn_s_waitcnt(0x0F78);   // vmcnt(8)
        } else {
            __builtin_amdgcn_s_waitcnt(0x0F70);   // vmcnt(0)
        }
        __asm__ volatile("" ::: "memory");

        const unsigned short* kb = &smem[bi * 8 * 512];
        const unsigned short* vb = kb + 4 * 512;

        // ---- GEMM1 (fp16 32x32x16): Sc^T[kk 32][m 32] x2 mt, d=64 ----
        fx16 sa[2] = {};
        #pragma unroll
        for (int ks = 0; ks < 4; ++ks) {
            h16x8 a = *(const h16x8*)(kb + ks * 512 + lane * 8);
            #pragma unroll
            for (int mt = 0; mt < 2; ++mt)
                sa[mt] = __builtin_amdgcn_mfma_f32_32x32x16_f16(a, qf[mt][ks], sa[mt], 0, 0, 0);
        }

        // ---- P = exp2(Sc^T') in regs, bf16-pair packed ----
        unsigned p01[2][8];
        #pragma unroll
        for (int mt = 0; mt < 2; ++mt)
            #pragma unroll
            for (int rp = 0; rp < 8; ++rp)
                p01[mt][rp] = pack_bf16(ex2(sa[mt][2 * rp]), ex2(sa[mt][2 * rp + 1]));

        // ---- C-layout -> GEMM2 A-layout: cross-half exchange ----
        union frag { unsigned u[4]; s16x8 v; };
        frag A[2][2];   // [mt][u]
        #pragma unroll
        for (int mt = 0; mt < 2; ++mt) {
#if __has_builtin(__builtin_amdgcn_permlane32_swap)
            typedef unsigned uix2 __attribute__((ext_vector_type(2)));
            uix2 r0 = __builtin_amdgcn_permlane32_swap(p01[mt][0], p01[mt][2], false, false);
            uix2 r1 = __builtin_amdgcn_permlane32_swap(p01[mt][1], p01[mt][3], false, false);
            A[mt][0].u[0] = r0.x; A[mt][0].u[1] = r1.x;
            A[mt][0].u[2] = r0.y; A[mt][0].u[3] = r1.y;
            uix2 r2 = __builtin_amdgcn_permlane32_swap(p01[mt][4], p01[mt][6], false, false);
            uix2 r3 = __builtin_amdgcn_permlane32_swap(p01[mt][5], p01[mt][7], false, false);
            A[mt][1].u[0] = r2.x; A[mt][1].u[1] = r3.x;
            A[mt][1].u[2] = r2.y; A[mt][1].u[3] = r3.y;
#else
            unsigned sw[8];
            #pragma unroll
            for (int rp = 0; rp < 8; ++rp)
                sw[rp] = (unsigned)__shfl_xor((int)p01[mt][rp], 32, 64);
            A[mt][0].u[0] = h ? sw[2]        : p01[mt][0];
            A[mt][0].u[1] = h ? sw[3]        : p01[mt][1];
            A[mt][0].u[2] = h ? p01[mt][2]   : sw[0];
            A[mt][0].u[3] = h ? p01[mt][3]   : sw[1];
            A[mt][1].u[0] = h ? sw[6]        : p01[mt][4];
            A[mt][1].u[1] = h ? sw[7]        : p01[mt][5];
            A[mt][1].u[2] = h ? p01[mt][6]   : sw[4];
            A[mt][1].u[3] = h ? p01[mt][7]   : sw[5];
#endif
        }

        // ---- GEMM2 (bf16 32x32x16): O += P*V over this wave's 32 kk ----
        // local V chunk for (u,dt) = u*2+dt  (global chunk kkq*4+u*2+dt).
        #pragma unroll
        for (int u = 0; u < 2; ++u) {
            #pragma unroll
            for (int dt = 0; dt < 2; ++dt) {
                s16x8 vv = *(const s16x8*)(vb + (u * 2 + dt) * 512 + lane * 8);
                #pragma unroll
                for (int mt = 0; mt < 2; ++mt)
                    oacc[mt][dt] = __builtin_amdgcn_mfma_f32_32x32x16_bf16(
                        A[mt][u].v, vv, oacc[mt][dt], 0, 0, 0);
            }
        }

        // Refill the buffer we just finished reading (tile i+2). Own loads,
        // own buffer -> safe without any synchronization.
        if (i + 2 < HALF_TILES) issue(t0 + i + 2, bi);
    }

    // ---- epilogue: direct streaming store of this wave's 64x64 partial.
    //      No LDS, no syncs. partial index = kh*4+kkq (8 disjoint copies). ----
    float* pout = partial + (((size_t)(kh * 4 + kkq)) * 4 + b) * S * D;
    #pragma unroll
    for (int dt = 0; dt < 2; ++dt)
        #pragma unroll
        for (int mt = 0; mt < 2; ++mt)
            #pragma unroll
            for (int r = 0; r < 16; ++r) {
                int row = q0 + mt * 32 + (r & 3) + 8 * (r >> 2) + 4 * h;
                pout[(size_t)row * D + dt * 32 + m5] = oacc[mt][dt][r];
            }
}

// ---------------- final reduce: out = sum of 8 partials ----------------
__global__ __launch_bounds__(256) void reduce_out8(
    const float4* __restrict__ p, float4* __restrict__ o, int n4)
{
    int i = blockIdx.x * 256 + threadIdx.x;
    if (i < n4) {
        float4 a = p[i];
        #pragma unroll
        for (int j = 1; j < 8; ++j) {
            float4 x = p[(size_t)j * n4 + i];
            a.x += x.x; a.y += x.y; a.z += x.z; a.w += x.w;
        }
        o[i] = a;
    }
}

// ---------------- fallback (known-good round-2 kernel) ----------------
__global__ __launch_bounds__(1024) void attn_fallback(
    const float* __restrict__ q, const float* __restrict__ k,
    const float* __restrict__ v, float* __restrict__ out)
{
    __shared__ unsigned short Kh[64][72];
    __shared__ unsigned short Kl[64][72];
    __shared__ unsigned short Vt[64][68];
    __shared__ unsigned short Pf[64][72];

    const int tid = threadIdx.x, lane = tid & 63, wave = tid >> 6;
    const int quad = lane >> 4, tq = lane & 15;
    const int kkb = wave & 3, mba = wave >> 2;
    const int b = blockIdx.y, q0 = blockIdx.x * 64;
    const float* qb = q + (size_t)b * S * D;
    const float* kb = k + (size_t)b * S * D;
    const float* vb = v + (size_t)b * S * D;
    float* ob = out + (size_t)b * S * D;

    s16x8 qh[2], ql[2];
    {
        const float* qrow = qb + (size_t)(q0 + mba * 16 + tq) * D;
        #pragma unroll
        for (int ks = 0; ks < 2; ++ks) {
            const float* src = qrow + ks * 32 + quad * 8;
            float4 f0 = *(const float4*)src;
            float4 f1 = *(const float4*)(src + 4);
            float f[8] = {f0.x, f0.y, f0.z, f0.w, f1.x, f1.y, f1.z, f1.w};
            #pragma unroll
            for (int j = 0; j < 8; ++j) {
                unsigned short hh = f2bf(f[j]);
                qh[ks][j] = (short)hh;
                ql[ks][j] = (short)f2bf(f[j] - bf2f(hh));
            }
        }
    }
    fx4 oacc = {0.f, 0.f, 0.f, 0.f};
    const int krow = tid >> 4, kc4 = (tid & 15) << 2;
    const int vd = tid & 63, vk = (tid >> 6) << 2;

    for (int t = 0; t < S / 64; ++t) {
        __syncthreads();
        const float* kt = kb + (size_t)(t * 64 + krow) * D;
        const float* vt = vb + (size_t)(t * 64 + vk) * D;
        {
            float4 kv = *(const float4*)(kt + kc4);
            unsigned short h0 = f2bf(kv.x), h1 = f2bf(kv.y), h2 = f2bf(kv.z), h3 = f2bf(kv.w);
            s16x4 a = {(short)h0, (short)h1, (short)h2, (short)h3};
            s16x4 l4 = {(short)f2bf(kv.x - bf2f(h0)), (short)f2bf(kv.y - bf2f(h1)),
                        (short)f2bf(kv.z - bf2f(h2)), (short)f2bf(kv.w - bf2f(h3))};
            *(s16x4*)&Kh[krow][kc4] = a;
            *(s16x4*)&Kl[krow][kc4] = l4;
            const float* vs = vt + vd;
            s16x4 vv = {(short)f2bf(vs[0]), (short)f2bf(vs[D]),
                        (short)f2bf(vs[2 * D]), (short)f2bf(vs[3 * D])};
            *(s16x4*)&Vt[vd][vk] = vv;
        }
        __syncthreads();
        fx4 sacc = {0.f, 0.f, 0.f, 0.f};
        #pragma unroll
        for (int ks = 0; ks < 2; ++ks) {
            s16x8 kah = *(const s16x8*)&Kh[kkb * 16 + tq][ks * 32 + quad * 8];
            s16x8 kal = *(const s16x8*)&Kl[kkb * 16 + tq][ks * 32 + quad * 8];
            sacc = __builtin_amdgcn_mfma_f32_16x16x32_bf16(kah, qh[ks], sacc, 0, 0, 0);
            sacc = __builtin_amdgcn_mfma_f32_16x16x32_bf16(kah, ql[ks], sacc, 0, 0, 0);
            sacc = __builtin_amdgcn_mfma_f32_16x16x32_bf16(kal, qh[ks], sacc, 0, 0, 0);
        }
        s16x4 pp = {(short)f2bf(__expf(sacc[0])), (short)f2bf(__expf(sacc[1])),
                    (short)f2bf(__expf(sacc[2])), (short)f2bf(__expf(sacc[3]))};
        *(s16x4*)&Pf[mba * 16 + tq][kkb * 16 + (quad << 2)] = pp;
        __syncthreads();
        #pragma unroll
        for (int ks = 0; ks < 2; ++ks) {
            s16x8 pa = *(const s16x8*)&Pf[mba * 16 + tq][ks * 32 + quad * 8];
            const unsigned short* vr = &Vt[kkb * 16 + tq][ks * 32 + quad * 8];
            s16x4 va = *(const s16x4*)vr;
            s16x4 vb2 = *(const s16x4*)(vr + 4);
            s16x8 vfull = __builtin_shufflevector(va, vb2, 0, 1, 2, 3, 4, 5, 6, 7);
            oacc = __builtin_amdgcn_mfma_f32_16x16x32_bf16(pa, vfull, oacc, 0, 0, 0);
        }
    }
    #pragma unroll
    for (int r = 0; r < 4; ++r)
        ob[(size_t)(q0 + mba * 16 + quad * 4 + r) * D + kkb * 16 + tq] = oacc[r];
}

extern "C" void kernel_launch(void* const* d_in, const int* in_sizes, int n_in,
                              void* d_out, int out_size, void* d_ws, size_t ws_size,
                              hipStream_t stream) {
    const float* q = (const float*)d_in[0];
    const float* k = (const float*)d_in[1];
    const float* v = (const float*)d_in[2];
    float* out = (float*)d_out;
    const int nbatch = in_sizes[0] / (S * D);   // 4
    const size_t elems = (size_t)nbatch * S * D;

    // ws: kf (fp16, 2MB) | vf (bf16, 2MB) | partial[8] (fp32, 32MB) = 36MB
    const size_t need = elems * 2 * 2 + elems * 8 * 4;
    if (nbatch == 4 && ws_size >= need && d_ws != nullptr) {
        unsigned short* kf = (unsigned short*)d_ws;
        unsigned short* vf = kf + elems;
        float* partial = (float*)(vf + elems);

        prep2<<<nbatch * TILES * 2, 256, 0, stream>>>(k, v, kf, vf);
        attn_main8<<<2048, 64, 0, stream>>>(q, kf, vf, partial);
        const int n4 = (int)(elems / 4);
        reduce_out8<<<(n4 + 255) / 256, 256, 0, stream>>>(
            (const float4*)partial, (float4*)out, n4);
    } else {
        dim3 grid(S / 64, nbatch);
        attn_fallback<<<grid, 1024, 0, stream>>>(q, k, v, out);
    }
}

// Round 12
// 99.275 us; speedup vs baseline: 1.4084x; 1.0042x over previous
//
#include <hip/hip_runtime.h>
#include <hip/hip_bf16.h>

// out = exp(Q K^T) V, unnormalized. B=4, S=4096, D=64, fp32 in/out.
// Round 18: REGISTERS-DIRECT main loop -- the LDS staging was a no-op.
// Discovery (from R17's chunk algebra): the DMA'd chunk bytes and the
// ds_read_b128 consumer bytes are IDENTICAL per lane (prep2 already put
// kf/vf in fragment order; chunk c, lane L: write [c*1024+L*16) ==
// read kb+ks*512+lane*8). 11 rounds of sync-structure work optimized a
// pass-through. Fix: load fragments straight to VGPRs with coalesced
// global_load_dwordx4 (16B/lane), register ping-pong double-buffer
// (manually unrolled x2, named arrays -- no dynamic indexing/scratch),
// compiler-managed waitcnt. No LDS, no barriers, no asm in the loop.
// Kept from R17 (verified): prep2, 1-wave blocks (2048 = 8 waves/CU),
// XCD slice pin (bid&7), direct reg->partial[8] epilogue, reduce_out8.
// NO launch_bounds min-waves (R16 lesson: the cap caused spill).

typedef short    s16x4 __attribute__((ext_vector_type(4)));
typedef short    s16x8 __attribute__((ext_vector_type(8)));
typedef _Float16 h16x8 __attribute__((ext_vector_type(8)));
typedef float    fx4   __attribute__((ext_vector_type(4)));
typedef float    fx16  __attribute__((ext_vector_type(16)));

constexpr int S = 4096, D = 64, BN = 128;
constexpr int TILES = S / BN;                       // 32
constexpr int HALF_TILES = TILES / 2;               // 16 per kk-half
constexpr int TILE_SHORTS  = 16 * 512;              // 16KB per array per tile
constexpr int BATCH_SHORTS = TILES * TILE_SHORTS;   // 262144

__device__ __forceinline__ unsigned short f2bf(float x) {
    unsigned u = __float_as_uint(x);
    u = (u + 0x7FFFu + ((u >> 16) & 1u)) >> 16;   // RNE
    return (unsigned short)u;
}
__device__ __forceinline__ float bf2f(unsigned short h) {
    return __uint_as_float(((unsigned)h) << 16);
}
__device__ __forceinline__ unsigned short f2h(float x) {
    union { _Float16 h; unsigned short s; } u;
    u.h = (_Float16)x;
    return u.s;
}
__device__ __forceinline__ unsigned pack_bf16(float lo, float hi) {
    __hip_bfloat162 r = __float22bfloat162_rn(make_float2(lo, hi));
    union { __hip_bfloat162 b; unsigned u; } c;
    c.b = r;
    return c.u;
}
__device__ __forceinline__ float ex2(float x) {
#if __has_builtin(__builtin_amdgcn_exp2f)
    return __builtin_amdgcn_exp2f(x);
#else
    return exp2f(x);
#endif
}

// -------- prep: K -> fp16 A-frag order, V -> bf16 B-frag order (32x32x16) ---
// K chunk c = kkq*4+ks : [lane][j] = K[t*128 + kkq*32 + (lane&31)][ks*16 + (lane>>5)*8 + j]
// V chunk c = ss*2+dt  : [lane][j] = V[t*128 + ss*16 + (lane>>5)*8 + j][dt*32 + (lane&31)]
__global__ __launch_bounds__(256) void prep2(
    const float* __restrict__ k, const float* __restrict__ v,
    unsigned short* __restrict__ kf, unsigned short* __restrict__ vf)
{
    __shared__ unsigned short tile[128 * 72];   // row stride 72 halves (pad)
    const int tid   = threadIdx.x;
    const int which = blockIdx.x & 1;           // 0 = K, 1 = V
    const int t     = (blockIdx.x >> 1) & 31;
    const int b     = blockIdx.x >> 6;
    const float* src = (which ? v : k) + ((size_t)b * S + t * BN) * D;

    #pragma unroll
    for (int i = 0; i < 8; ++i) {               // coalesced: 2048 float4s/block
        int f   = i * 256 + tid;
        int row = f >> 4;
        int c4  = (f & 15) << 2;
        float4 x = *(const float4*)(src + row * D + c4);
        s16x4 o;
        if (which) o = (s16x4){(short)f2bf(x.x), (short)f2bf(x.y),
                               (short)f2bf(x.z), (short)f2bf(x.w)};
        else       o = (s16x4){(short)f2h(x.x), (short)f2h(x.y),
                               (short)f2h(x.z), (short)f2h(x.w)};
        *(s16x4*)&tile[row * 72 + c4] = o;
    }
    __syncthreads();

    const int lane = tid & 63;
    unsigned short* dst = (which ? vf : kf) + (size_t)b * BATCH_SHORTS + t * TILE_SHORTS;
    #pragma unroll
    for (int i = 0; i < 4; ++i) {
        int c = (tid >> 6) * 4 + i;             // chunk 0..15
        s16x8 o;
        if (which == 0) {
            int row = (c >> 2) * 32 + (lane & 31);
            int dc  = (c & 3) * 16 + (lane >> 5) * 8;
            o = *(const s16x8*)&tile[row * 72 + dc];     // b128, aligned
        } else {
            int r0 = (c >> 1) * 16 + (lane >> 5) * 8;
            int dc = (c & 1) * 32 + (lane & 31);
            #pragma unroll
            for (int j = 0; j < 8; ++j) o[j] = (short)tile[(r0 + j) * 72 + dc];
        }
        *(s16x8*)(dst + c * 512 + lane * 8) = o;         // coalesced b128
    }
}

// -------- main: ONE WAVE per block, registers-direct, no LDS at all -------
// 2048 blocks x 64 thr (8 waves/CU). Each wave owns 64 q-rows x one
// (kh,kkq) kk slice; fragments load straight to VGPRs (16B/lane coalesced).
__global__ __launch_bounds__(64) void attn_main9(
    const float* __restrict__ q, const unsigned short* __restrict__ kf,
    const unsigned short* __restrict__ vf, float* __restrict__ partial)
{
    const int lane = threadIdx.x;               // 0..63 (one wave)
    const int h = lane >> 5, m5 = lane & 31;
    const int bid = blockIdx.x;
    const int slice = bid & 7;                  // -> XCD pin (%8 round-robin)
    const int b = slice >> 1;                   // batch 0..3
    const int kh = slice & 1;                   // kk-half 0/1
    const int idx = bid >> 3;                   // 0..255 = qb*4 + kkq
    const int kkq = idx & 3;                    // kk-quarter within tile
    const int q0 = (idx >> 2) * 64;             // 64 q-rows per wave
    const int t0 = kh * HALF_TILES;

    // Per-wave fragment base: chunks kkq*4 .. kkq*4+3, this lane's 16B.
    const unsigned short* kwb = kf + (size_t)b * BATCH_SHORTS + kkq * 4 * 512 + lane * 8;
    const unsigned short* vwb = vf + (size_t)b * BATCH_SHORTS + kkq * 4 * 512 + lane * 8;

    // Q B-frags fp16, pre-scaled by log2(e) so exp(s) = exp2(s').
    const float LOG2E = 1.4426950408889634f;
    h16x8 qf[2][4];   // [mt][ks]
    #pragma unroll
    for (int mt = 0; mt < 2; ++mt) {
        const float* qrow = q + ((size_t)b * S + q0 + mt * 32 + m5) * D + h * 8;
        #pragma unroll
        for (int ks = 0; ks < 4; ++ks) {
            float4 a = *(const float4*)(qrow + ks * 16);
            float4 c = *(const float4*)(qrow + ks * 16 + 4);
            qf[mt][ks] = (h16x8){
                (_Float16)(a.x * LOG2E), (_Float16)(a.y * LOG2E),
                (_Float16)(a.z * LOG2E), (_Float16)(a.w * LOG2E),
                (_Float16)(c.x * LOG2E), (_Float16)(c.y * LOG2E),
                (_Float16)(c.z * LOG2E), (_Float16)(c.w * LOG2E)};
        }
    }

    fx16 oacc[2][2] = {};   // [mt][dt]

    // Register double-buffer (named arrays; all indices compile-time).
    h16x8 kA0[4], kA1[4];
    s16x8 vB0[4], vB1[4];

    auto loadKV = [&](int t, h16x8* kA, s16x8* vB) {
        const unsigned short* kt = kwb + (size_t)t * TILE_SHORTS;
        const unsigned short* vt = vwb + (size_t)t * TILE_SHORTS;
        #pragma unroll
        for (int c = 0; c < 4; ++c) {
            kA[c] = *(const h16x8*)(kt + c * 512);   // global_load_dwordx4
            vB[c] = *(const s16x8*)(vt + c * 512);
        }
    };

    auto computeTile = [&](const h16x8* kA, const s16x8* vB) {
        // ---- GEMM1 (fp16 32x32x16): Sc^T[kk 32][m 32] x2 mt, d=64 ----
        fx16 sa[2] = {};
        #pragma unroll
        for (int ks = 0; ks < 4; ++ks)
            #pragma unroll
            for (int mt = 0; mt < 2; ++mt)
                sa[mt] = __builtin_amdgcn_mfma_f32_32x32x16_f16(kA[ks], qf[mt][ks], sa[mt], 0, 0, 0);

        // ---- P = exp2(Sc^T') in regs, bf16-pair packed ----
        unsigned p01[2][8];
        #pragma unroll
        for (int mt = 0; mt < 2; ++mt)
            #pragma unroll
            for (int rp = 0; rp < 8; ++rp)
                p01[mt][rp] = pack_bf16(ex2(sa[mt][2 * rp]), ex2(sa[mt][2 * rp + 1]));

        // ---- C-layout -> GEMM2 A-layout: cross-half exchange ----
        union frag { unsigned u[4]; s16x8 v; };
        frag A[2][2];   // [mt][u]
        #pragma unroll
        for (int mt = 0; mt < 2; ++mt) {
#if __has_builtin(__builtin_amdgcn_permlane32_swap)
            typedef unsigned uix2 __attribute__((ext_vector_type(2)));
            uix2 r0 = __builtin_amdgcn_permlane32_swap(p01[mt][0], p01[mt][2], false, false);
            uix2 r1 = __builtin_amdgcn_permlane32_swap(p01[mt][1], p01[mt][3], false, false);
            A[mt][0].u[0] = r0.x; A[mt][0].u[1] = r1.x;
            A[mt][0].u[2] = r0.y; A[mt][0].u[3] = r1.y;
            uix2 r2 = __builtin_amdgcn_permlane32_swap(p01[mt][4], p01[mt][6], false, false);
            uix2 r3 = __builtin_amdgcn_permlane32_swap(p01[mt][5], p01[mt][7], false, false);
            A[mt][1].u[0] = r2.x; A[mt][1].u[1] = r3.x;
            A[mt][1].u[2] = r2.y; A[mt][1].u[3] = r3.y;
#else
            unsigned sw[8];
            #pragma unroll
            for (int rp = 0; rp < 8; ++rp)
                sw[rp] = (unsigned)__shfl_xor((int)p01[mt][rp], 32, 64);
            A[mt][0].u[0] = h ? sw[2]        : p01[mt][0];
            A[mt][0].u[1] = h ? sw[3]        : p01[mt][1];
            A[mt][0].u[2] = h ? p01[mt][2]   : sw[0];
            A[mt][0].u[3] = h ? p01[mt][3]   : sw[1];
            A[mt][1].u[0] = h ? sw[6]        : p01[mt][4];
            A[mt][1].u[1] = h ? sw[7]        : p01[mt][5];
            A[mt][1].u[2] = h ? p01[mt][6]   : sw[4];
            A[mt][1].u[3] = h ? p01[mt][7]   : sw[5];
#endif
        }

        // ---- GEMM2 (bf16 32x32x16): O += P*V over this wave's 32 kk ----
        // V frag for (u,dt) = vB[u*2+dt]  (global chunk kkq*4+u*2+dt).
        #pragma unroll
        for (int u = 0; u < 2; ++u)
            #pragma unroll
            for (int dt = 0; dt < 2; ++dt)
                #pragma unroll
                for (int mt = 0; mt < 2; ++mt)
                    oacc[mt][dt] = __builtin_amdgcn_mfma_f32_32x32x16_bf16(
                        A[mt][u].v, vB[u * 2 + dt], oacc[mt][dt], 0, 0, 0);
    };

    loadKV(t0, kA0, vB0);
    // Unrolled-by-2 ping-pong: prefetch i+1 into the idle buffer while
    // computing i; compiler inserts fine-grained vmcnt via register deps.
    for (int i = 0; i < HALF_TILES; i += 2) {
        if (i + 1 < HALF_TILES) loadKV(t0 + i + 1, kA1, vB1);
        computeTile(kA0, vB0);
        if (i + 2 < HALF_TILES) loadKV(t0 + i + 2, kA0, vB0);
        computeTile(kA1, vB1);
    }

    // ---- epilogue: direct streaming store of this wave's 64x64 partial.
    //      partial copy index = kh*4+kkq (8 disjoint copies x 4 batches). ----
    float* pout = partial + (((size_t)(kh * 4 + kkq)) * 4 + b) * S * D;
    #pragma unroll
    for (int dt = 0; dt < 2; ++dt)
        #pragma unroll
        for (int mt = 0; mt < 2; ++mt)
            #pragma unroll
            for (int r = 0; r < 16; ++r) {
                int row = q0 + mt * 32 + (r & 3) + 8 * (r >> 2) + 4 * h;
                pout[(size_t)row * D + dt * 32 + m5] = oacc[mt][dt][r];
            }
}

// ---------------- final reduce: out = sum of 8 partials ----------------
__global__ __launch_bounds__(256) void reduce_out8(
    const float4* __restrict__ p, float4* __restrict__ o, int n4)
{
    int i = blockIdx.x * 256 + threadIdx.x;
    if (i < n4) {
        float4 a = p[i];
        #pragma unroll
        for (int j = 1; j < 8; ++j) {
            float4 x = p[(size_t)j * n4 + i];
            a.x += x.x; a.y += x.y; a.z += x.z; a.w += x.w;
        }
        o[i] = a;
    }
}

// ---------------- fallback (known-good round-2 kernel) ----------------
__global__ __launch_bounds__(1024) void attn_fallback(
    const float* __restrict__ q, const float* __restrict__ k,
    const float* __restrict__ v, float* __restrict__ out)
{
    __shared__ unsigned short Kh[64][72];
    __shared__ unsigned short Kl[64][72];
    __shared__ unsigned short Vt[64][68];
    __shared__ unsigned short Pf[64][72];

    const int tid = threadIdx.x, lane = tid & 63, wave = tid >> 6;
    const int quad = lane >> 4, tq = lane & 15;
    const int kkb = wave & 3, mba = wave >> 2;
    const int b = blockIdx.y, q0 = blockIdx.x * 64;
    const float* qb = q + (size_t)b * S * D;
    const float* kb = k + (size_t)b * S * D;
    const float* vb = v + (size_t)b * S * D;
    float* ob = out + (size_t)b * S * D;

    s16x8 qh[2], ql[2];
    {
        const float* qrow = qb + (size_t)(q0 + mba * 16 + tq) * D;
        #pragma unroll
        for (int ks = 0; ks < 2; ++ks) {
            const float* src = qrow + ks * 32 + quad * 8;
            float4 f0 = *(const float4*)src;
            float4 f1 = *(const float4*)(src + 4);
            float f[8] = {f0.x, f0.y, f0.z, f0.w, f1.x, f1.y, f1.z, f1.w};
            #pragma unroll
            for (int j = 0; j < 8; ++j) {
                unsigned short hh = f2bf(f[j]);
                qh[ks][j] = (short)hh;
                ql[ks][j] = (short)f2bf(f[j] - bf2f(hh));
            }
        }
    }
    fx4 oacc = {0.f, 0.f, 0.f, 0.f};
    const int krow = tid >> 4, kc4 = (tid & 15) << 2;
    const int vd = tid & 63, vk = (tid >> 6) << 2;

    for (int t = 0; t < S / 64; ++t) {
        __syncthreads();
        const float* kt = kb + (size_t)(t * 64 + krow) * D;
        const float* vt = vb + (size_t)(t * 64 + vk) * D;
        {
            float4 kv = *(const float4*)(kt + kc4);
            unsigned short h0 = f2bf(kv.x), h1 = f2bf(kv.y), h2 = f2bf(kv.z), h3 = f2bf(kv.w);
            s16x4 a = {(short)h0, (short)h1, (short)h2, (short)h3};
            s16x4 l4 = {(short)f2bf(kv.x - bf2f(h0)), (short)f2bf(kv.y - bf2f(h1)),
                        (short)f2bf(kv.z - bf2f(h2)), (short)f2bf(kv.w - bf2f(h3))};
            *(s16x4*)&Kh[krow][kc4] = a;
            *(s16x4*)&Kl[krow][kc4] = l4;
            const float* vs = vt + vd;
            s16x4 vv = {(short)f2bf(vs[0]), (short)f2bf(vs[D]),
                        (short)f2bf(vs[2 * D]), (short)f2bf(vs[3 * D])};
            *(s16x4*)&Vt[vd][vk] = vv;
        }
        __syncthreads();
        fx4 sacc = {0.f, 0.f, 0.f, 0.f};
        #pragma unroll
        for (int ks = 0; ks < 2; ++ks) {
            s16x8 kah = *(const s16x8*)&Kh[kkb * 16 + tq][ks * 32 + quad * 8];
            s16x8 kal = *(const s16x8*)&Kl[kkb * 16 + tq][ks * 32 + quad * 8];
            sacc = __builtin_amdgcn_mfma_f32_16x16x32_bf16(kah, qh[ks], sacc, 0, 0, 0);
            sacc = __builtin_amdgcn_mfma_f32_16x16x32_bf16(kah, ql[ks], sacc, 0, 0, 0);
            sacc = __builtin_amdgcn_mfma_f32_16x16x32_bf16(kal, qh[ks], sacc, 0, 0, 0);
        }
        s16x4 pp = {(short)f2bf(__expf(sacc[0])), (short)f2bf(__expf(sacc[1])),
                    (short)f2bf(__expf(sacc[2])), (short)f2bf(__expf(sacc[3]))};
        *(s16x4*)&Pf[mba * 16 + tq][kkb * 16 + (quad << 2)] = pp;
        __syncthreads();
        #pragma unroll
        for (int ks = 0; ks < 2; ++ks) {
            s16x8 pa = *(const s16x8*)&Pf[mba * 16 + tq][ks * 32 + quad * 8];
            const unsigned short* vr = &Vt[kkb * 16 + tq][ks * 32 + quad * 8];
            s16x4 va = *(const s16x4*)vr;
            s16x4 vb2 = *(const s16x4*)(vr + 4);
            s16x8 vfull = __builtin_shufflevector(va, vb2, 0, 1, 2, 3, 4, 5, 6, 7);
            oacc = __builtin_amdgcn_mfma_f32_16x16x32_bf16(pa, vfull, oacc, 0, 0, 0);
        }
    }
    #pragma unroll
    for (int r = 0; r < 4; ++r)
        ob[(size_t)(q0 + mba * 16 + quad * 4 + r) * D + kkb * 16 + tq] = oacc[r];
}

extern "C" void kernel_launch(void* const* d_in, const int* in_sizes, int n_in,
                              void* d_out, int out_size, void* d_ws, size_t ws_size,
                              hipStream_t stream) {
    const float* q = (const float*)d_in[0];
    const float* k = (const float*)d_in[1];
    const float* v = (const float*)d_in[2];
    float* out = (float*)d_out;
    const int nbatch = in_sizes[0] / (S * D);   // 4
    const size_t elems = (size_t)nbatch * S * D;

    // ws: kf (fp16, 2MB) | vf (bf16, 2MB) | partial[8] (fp32, 32MB) = 36MB
    const size_t need = elems * 2 * 2 + elems * 8 * 4;
    if (nbatch == 4 && ws_size >= need && d_ws != nullptr) {
        unsigned short* kf = (unsigned short*)d_ws;
        unsigned short* vf = kf + elems;
        float* partial = (float*)(vf + elems);

        prep2<<<nbatch * TILES * 2, 256, 0, stream>>>(k, v, kf, vf);
        attn_main9<<<2048, 64, 0, stream>>>(q, kf, vf, partial);
        const int n4 = (int)(elems / 4);
        reduce_out8<<<(n4 + 255) / 256, 256, 0, stream>>>(
            (const float4*)partial, (float4*)out, n4);
    } else {
        dim3 grid(S / 64, nbatch);
        attn_fallback<<<grid, 1024, 0, stream>>>(q, k, v, out);
    }
}

// Round 14
// 96.646 us; speedup vs baseline: 1.4467x; 1.0272x over previous
//
#include <hip/hip_runtime.h>
#include <hip/hip_bf16.h>

// out = exp(Q K^T) V, unnormalized. B=4, S=4096, D=64, fp32 in/out.
// Round 20 (= round 19 resubmitted after infra failure; never measured).
// CACHE-BROADCAST blocks -- kill aggregate load pressure.
// R18 (registers-direct, no LDS/barriers) stayed at ~2.5us/tile like every
// variant since R6. Last suspect: load-stream queuing. R18's 2048 free
// waves demanded 256MB against 4MB of kf/vf with ~8 loads in flight each
// (Little's law: 78TB/s needed vs 34.5TB/s L2 ceiling -> latency inflates).
// Fix: 8 waves per 512-thr block, all waves SAME (b,kh,kkq) kk-slice,
// DIFFERENT q-rows (512/block). All 8 issue IDENTICAL kf/vf addresses per
// tile -> 7/8 loads are L1 hits (16KB/tile << 32KB L1); unique demand
// 256MB -> 32MB. No LDS, no barriers (sharing is implicit via L1).
// Grid 256 (8 qg x 4 b x 8 kslice); kslice=bid&7 pins 512KB/XCD L2.
// Per-wave code byte-identical to R18's verified computeTile/loadKV.
// Epilogue reg->partial[8] + reduce_out8 unchanged (R18-verified).

typedef short    s16x4 __attribute__((ext_vector_type(4)));
typedef short    s16x8 __attribute__((ext_vector_type(8)));
typedef _Float16 h16x8 __attribute__((ext_vector_type(8)));
typedef float    fx4   __attribute__((ext_vector_type(4)));
typedef float    fx16  __attribute__((ext_vector_type(16)));

constexpr int S = 4096, D = 64, BN = 128;
constexpr int TILES = S / BN;                       // 32
constexpr int HALF_TILES = TILES / 2;               // 16 per kk-half
constexpr int TILE_SHORTS  = 16 * 512;              // 16KB per array per tile
constexpr int BATCH_SHORTS = TILES * TILE_SHORTS;   // 262144

__device__ __forceinline__ unsigned short f2bf(float x) {
    unsigned u = __float_as_uint(x);
    u = (u + 0x7FFFu + ((u >> 16) & 1u)) >> 16;   // RNE
    return (unsigned short)u;
}
__device__ __forceinline__ float bf2f(unsigned short h) {
    return __uint_as_float(((unsigned)h) << 16);
}
__device__ __forceinline__ unsigned short f2h(float x) {
    union { _Float16 h; unsigned short s; } u;
    u.h = (_Float16)x;
    return u.s;
}
__device__ __forceinline__ unsigned pack_bf16(float lo, float hi) {
    __hip_bfloat162 r = __float22bfloat162_rn(make_float2(lo, hi));
    union { __hip_bfloat162 b; unsigned u; } c;
    c.b = r;
    return c.u;
}
__device__ __forceinline__ float ex2(float x) {
#if __has_builtin(__builtin_amdgcn_exp2f)
    return __builtin_amdgcn_exp2f(x);
#else
    return exp2f(x);
#endif
}

// -------- prep: K -> fp16 A-frag order, V -> bf16 B-frag order (32x32x16) ---
// K chunk c = kkq*4+ks : [lane][j] = K[t*128 + kkq*32 + (lane&31)][ks*16 + (lane>>5)*8 + j]
// V chunk c = ss*2+dt  : [lane][j] = V[t*128 + ss*16 + (lane>>5)*8 + j][dt*32 + (lane&31)]
__global__ __launch_bounds__(256) void prep2(
    const float* __restrict__ k, const float* __restrict__ v,
    unsigned short* __restrict__ kf, unsigned short* __restrict__ vf)
{
    __shared__ unsigned short tile[128 * 72];   // row stride 72 halves (pad)
    const int tid   = threadIdx.x;
    const int which = blockIdx.x & 1;           // 0 = K, 1 = V
    const int t     = (blockIdx.x >> 1) & 31;
    const int b     = blockIdx.x >> 6;
    const float* src = (which ? v : k) + ((size_t)b * S + t * BN) * D;

    #pragma unroll
    for (int i = 0; i < 8; ++i) {               // coalesced: 2048 float4s/block
        int f   = i * 256 + tid;
        int row = f >> 4;
        int c4  = (f & 15) << 2;
        float4 x = *(const float4*)(src + row * D + c4);
        s16x4 o;
        if (which) o = (s16x4){(short)f2bf(x.x), (short)f2bf(x.y),
                               (short)f2bf(x.z), (short)f2bf(x.w)};
        else       o = (s16x4){(short)f2h(x.x), (short)f2h(x.y),
                               (short)f2h(x.z), (short)f2h(x.w)};
        *(s16x4*)&tile[row * 72 + c4] = o;
    }
    __syncthreads();

    const int lane = tid & 63;
    unsigned short* dst = (which ? vf : kf) + (size_t)b * BATCH_SHORTS + t * TILE_SHORTS;
    #pragma unroll
    for (int i = 0; i < 4; ++i) {
        int c = (tid >> 6) * 4 + i;             // chunk 0..15
        s16x8 o;
        if (which == 0) {
            int row = (c >> 2) * 32 + (lane & 31);
            int dc  = (c & 3) * 16 + (lane >> 5) * 8;
            o = *(const s16x8*)&tile[row * 72 + dc];     // b128, aligned
        } else {
            int r0 = (c >> 1) * 16 + (lane >> 5) * 8;
            int dc = (c & 1) * 32 + (lane & 31);
            #pragma unroll
            for (int j = 0; j < 8; ++j) o[j] = (short)tile[(r0 + j) * 72 + dc];
        }
        *(s16x8*)(dst + c * 512 + lane * 8) = o;         // coalesced b128
    }
}

// -------- main: 8-wave blocks, cache-broadcast, registers-direct ----------
// 256 blocks x 512 thr. All 8 waves of a block: SAME (b,kh,kkq) kk-slice,
// DIFFERENT 64-row q-groups (512 q-rows/block). Identical kf/vf addresses
// across waves -> L1 broadcast. No LDS, no barriers.
__global__ __launch_bounds__(512) void attn_main10(
    const float* __restrict__ q, const unsigned short* __restrict__ kf,
    const unsigned short* __restrict__ vf, float* __restrict__ partial)
{
    const int tid = threadIdx.x, lane = tid & 63, w = tid >> 6;   // w 0..7
    const int h = lane >> 5, m5 = lane & 31;
    const int bid = blockIdx.x;
    const int kslice = bid & 7;                 // -> XCD pin (%8 round-robin)
    const int kh = kslice >> 2;                 // kk-half 0/1
    const int kkq = kslice & 3;                 // kk-quarter within tile
    const int rest = bid >> 3;                  // 0..31 = qg*4 + b
    const int b = rest & 3;                     // batch 0..3
    const int q0 = (rest >> 2) * 512 + w * 64;  // this wave's 64 q-rows
    const int t0 = kh * HALF_TILES;

    // Per-wave fragment base: chunks kkq*4 .. kkq*4+3, this lane's 16B.
    // IDENTICAL across the block's 8 waves -> L1-served broadcast.
    const unsigned short* kwb = kf + (size_t)b * BATCH_SHORTS + kkq * 4 * 512 + lane * 8;
    const unsigned short* vwb = vf + (size_t)b * BATCH_SHORTS + kkq * 4 * 512 + lane * 8;

    // Q B-frags fp16, pre-scaled by log2(e) so exp(s) = exp2(s').
    const float LOG2E = 1.4426950408889634f;
    h16x8 qf[2][4];   // [mt][ks]
    #pragma unroll
    for (int mt = 0; mt < 2; ++mt) {
        const float* qrow = q + ((size_t)b * S + q0 + mt * 32 + m5) * D + h * 8;
        #pragma unroll
        for (int ks = 0; ks < 4; ++ks) {
            float4 a = *(const float4*)(qrow + ks * 16);
            float4 c = *(const float4*)(qrow + ks * 16 + 4);
            qf[mt][ks] = (h16x8){
                (_Float16)(a.x * LOG2E), (_Float16)(a.y * LOG2E),
                (_Float16)(a.z * LOG2E), (_Float16)(a.w * LOG2E),
                (_Float16)(c.x * LOG2E), (_Float16)(c.y * LOG2E),
                (_Float16)(c.z * LOG2E), (_Float16)(c.w * LOG2E)};
        }
    }

    fx16 oacc[2][2] = {};   // [mt][dt]

    // Register double-buffer (named arrays; all indices compile-time).
    h16x8 kA0[4], kA1[4];
    s16x8 vB0[4], vB1[4];

    auto loadKV = [&](int t, h16x8* kA, s16x8* vB) {
        const unsigned short* kt = kwb + (size_t)t * TILE_SHORTS;
        const unsigned short* vt = vwb + (size_t)t * TILE_SHORTS;
        #pragma unroll
        for (int c = 0; c < 4; ++c) {
            kA[c] = *(const h16x8*)(kt + c * 512);   // global_load_dwordx4
            vB[c] = *(const s16x8*)(vt + c * 512);
        }
    };

    auto computeTile = [&](const h16x8* kA, const s16x8* vB) {
        // ---- GEMM1 (fp16 32x32x16): Sc^T[kk 32][m 32] x2 mt, d=64 ----
        fx16 sa[2] = {};
        #pragma unroll
        for (int ks = 0; ks < 4; ++ks)
            #pragma unroll
            for (int mt = 0; mt < 2; ++mt)
                sa[mt] = __builtin_amdgcn_mfma_f32_32x32x16_f16(kA[ks], qf[mt][ks], sa[mt], 0, 0, 0);

        // ---- P = exp2(Sc^T') in regs, bf16-pair packed ----
        unsigned p01[2][8];
        #pragma unroll
        for (int mt = 0; mt < 2; ++mt)
            #pragma unroll
            for (int rp = 0; rp < 8; ++rp)
                p01[mt][rp] = pack_bf16(ex2(sa[mt][2 * rp]), ex2(sa[mt][2 * rp + 1]));

        // ---- C-layout -> GEMM2 A-layout: cross-half exchange ----
        union frag { unsigned u[4]; s16x8 v; };
        frag A[2][2];   // [mt][u]
        #pragma unroll
        for (int mt = 0; mt < 2; ++mt) {
#if __has_builtin(__builtin_amdgcn_permlane32_swap)
            typedef unsigned uix2 __attribute__((ext_vector_type(2)));
            uix2 r0 = __builtin_amdgcn_permlane32_swap(p01[mt][0], p01[mt][2], false, false);
            uix2 r1 = __builtin_amdgcn_permlane32_swap(p01[mt][1], p01[mt][3], false, false);
            A[mt][0].u[0] = r0.x; A[mt][0].u[1] = r1.x;
            A[mt][0].u[2] = r0.y; A[mt][0].u[3] = r1.y;
            uix2 r2 = __builtin_amdgcn_permlane32_swap(p01[mt][4], p01[mt][6], false, false);
            uix2 r3 = __builtin_amdgcn_permlane32_swap(p01[mt][5], p01[mt][7], false, false);
            A[mt][1].u[0] = r2.x; A[mt][1].u[1] = r3.x;
            A[mt][1].u[2] = r2.y; A[mt][1].u[3] = r3.y;
#else
            unsigned sw[8];
            #pragma unroll
            for (int rp = 0; rp < 8; ++rp)
                sw[rp] = (unsigned)__shfl_xor((int)p01[mt][rp], 32, 64);
            A[mt][0].u[0] = h ? sw[2]        : p01[mt][0];
            A[mt][0].u[1] = h ? sw[3]        : p01[mt][1];
            A[mt][0].u[2] = h ? p01[mt][2]   : sw[0];
            A[mt][0].u[3] = h ? p01[mt][3]   : sw[1];
            A[mt][1].u[0] = h ? sw[6]        : p01[mt][4];
            A[mt][1].u[1] = h ? sw[7]        : p01[mt][5];
            A[mt][1].u[2] = h ? p01[mt][6]   : sw[4];
            A[mt][1].u[3] = h ? p01[mt][7]   : sw[5];
#endif
        }

        // ---- GEMM2 (bf16 32x32x16): O += P*V over this wave's 32 kk ----
        // V frag for (u,dt) = vB[u*2+dt]  (global chunk kkq*4+u*2+dt).
        #pragma unroll
        for (int u = 0; u < 2; ++u)
            #pragma unroll
            for (int dt = 0; dt < 2; ++dt)
                #pragma unroll
                for (int mt = 0; mt < 2; ++mt)
                    oacc[mt][dt] = __builtin_amdgcn_mfma_f32_32x32x16_bf16(
                        A[mt][u].v, vB[u * 2 + dt], oacc[mt][dt], 0, 0, 0);
    };

    loadKV(t0, kA0, vB0);
    // Unrolled-by-2 ping-pong: prefetch i+1 into the idle buffer while
    // computing i; compiler inserts fine-grained vmcnt via register deps.
    for (int i = 0; i < HALF_TILES; i += 2) {
        if (i + 1 < HALF_TILES) loadKV(t0 + i + 1, kA1, vB1);
        computeTile(kA0, vB0);
        if (i + 2 < HALF_TILES) loadKV(t0 + i + 2, kA0, vB0);
        computeTile(kA1, vB1);
    }

    // ---- epilogue: direct streaming store of this wave's 64x64 partial.
    //      partial copy index = kh*4+kkq (8 disjoint copies x 4 batches). ----
    float* pout = partial + (((size_t)(kh * 4 + kkq)) * 4 + b) * S * D;
    #pragma unroll
    for (int dt = 0; dt < 2; ++dt)
        #pragma unroll
        for (int mt = 0; mt < 2; ++mt)
            #pragma unroll
            for (int r = 0; r < 16; ++r) {
                int row = q0 + mt * 32 + (r & 3) + 8 * (r >> 2) + 4 * h;
                pout[(size_t)row * D + dt * 32 + m5] = oacc[mt][dt][r];
            }
}

// ---------------- final reduce: out = sum of 8 partials ----------------
__global__ __launch_bounds__(256) void reduce_out8(
    const float4* __restrict__ p, float4* __restrict__ o, int n4)
{
    int i = blockIdx.x * 256 + threadIdx.x;
    if (i < n4) {
        float4 a = p[i];
        #pragma unroll
        for (int j = 1; j < 8; ++j) {
            float4 x = p[(size_t)j * n4 + i];
            a.x += x.x; a.y += x.y; a.z += x.z; a.w += x.w;
        }
        o[i] = a;
    }
}

// ---------------- fallback (known-good round-2 kernel) ----------------
__global__ __launch_bounds__(1024) void attn_fallback(
    const float* __restrict__ q, const float* __restrict__ k,
    const float* __restrict__ v, float* __restrict__ out)
{
    __shared__ unsigned short Kh[64][72];
    __shared__ unsigned short Kl[64][72];
    __shared__ unsigned short Vt[64][68];
    __shared__ unsigned short Pf[64][72];

    const int tid = threadIdx.x, lane = tid & 63, wave = tid >> 6;
    const int quad = lane >> 4, tq = lane & 15;
    const int kkb = wave & 3, mba = wave >> 2;
    const int b = blockIdx.y, q0 = blockIdx.x * 64;
    const float* qb = q + (size_t)b * S * D;
    const float* kb = k + (size_t)b * S * D;
    const float* vb = v + (size_t)b * S * D;
    float* ob = out + (size_t)b * S * D;

    s16x8 qh[2], ql[2];
    {
        const float* qrow = qb + (size_t)(q0 + mba * 16 + tq) * D;
        #pragma unroll
        for (int ks = 0; ks < 2; ++ks) {
            const float* src = qrow + ks * 32 + quad * 8;
            float4 f0 = *(const float4*)src;
            float4 f1 = *(const float4*)(src + 4);
            float f[8] = {f0.x, f0.y, f0.z, f0.w, f1.x, f1.y, f1.z, f1.w};
            #pragma unroll
            for (int j = 0; j < 8; ++j) {
                unsigned short hh = f2bf(f[j]);
                qh[ks][j] = (short)hh;
                ql[ks][j] = (short)f2bf(f[j] - bf2f(hh));
            }
        }
    }
    fx4 oacc = {0.f, 0.f, 0.f, 0.f};
    const int krow = tid >> 4, kc4 = (tid & 15) << 2;
    const int vd = tid & 63, vk = (tid >> 6) << 2;

    for (int t = 0; t < S / 64; ++t) {
        __syncthreads();
        const float* kt = kb + (size_t)(t * 64 + krow) * D;
        const float* vt = vb + (size_t)(t * 64 + vk) * D;
        {
            float4 kv = *(const float4*)(kt + kc4);
            unsigned short h0 = f2bf(kv.x), h1 = f2bf(kv.y), h2 = f2bf(kv.z), h3 = f2bf(kv.w);
            s16x4 a = {(short)h0, (short)h1, (short)h2, (short)h3};
            s16x4 l4 = {(short)f2bf(kv.x - bf2f(h0)), (short)f2bf(kv.y - bf2f(h1)),
                        (short)f2bf(kv.z - bf2f(h2)), (short)f2bf(kv.w - bf2f(h3))};
            *(s16x4*)&Kh[krow][kc4] = a;
            *(s16x4*)&Kl[krow][kc4] = l4;
            const float* vs = vt + vd;
            s16x4 vv = {(short)f2bf(vs[0]), (short)f2bf(vs[D]),
                        (short)f2bf(vs[2 * D]), (short)f2bf(vs[3 * D])};
            *(s16x4*)&Vt[vd][vk] = vv;
        }
        __syncthreads();
        fx4 sacc = {0.f, 0.f, 0.f, 0.f};
        #pragma unroll
        for (int ks = 0; ks < 2; ++ks) {
            s16x8 kah = *(const s16x8*)&Kh[kkb * 16 + tq][ks * 32 + quad * 8];
            s16x8 kal = *(const s16x8*)&Kl[kkb * 16 + tq][ks * 32 + quad * 8];
            sacc = __builtin_amdgcn_mfma_f32_16x16x32_bf16(kah, qh[ks], sacc, 0, 0, 0);
            sacc = __builtin_amdgcn_mfma_f32_16x16x32_bf16(kah, ql[ks], sacc, 0, 0, 0);
            sacc = __builtin_amdgcn_mfma_f32_16x16x32_bf16(kal, qh[ks], sacc, 0, 0, 0);
        }
        s16x4 pp = {(short)f2bf(__expf(sacc[0])), (short)f2bf(__expf(sacc[1])),
                    (short)f2bf(__expf(sacc[2])), (short)f2bf(__expf(sacc[3]))};
        *(s16x4*)&Pf[mba * 16 + tq][kkb * 16 + (quad << 2)] = pp;
        __syncthreads();
        #pragma unroll
        for (int ks = 0; ks < 2; ++ks) {
            s16x8 pa = *(const s16x8*)&Pf[mba * 16 + tq][ks * 32 + quad * 8];
            const unsigned short* vr = &Vt[kkb * 16 + tq][ks * 32 + quad * 8];
            s16x4 va = *(const s16x4*)vr;
            s16x4 vb2 = *(const s16x4*)(vr + 4);
            s16x8 vfull = __builtin_shufflevector(va, vb2, 0, 1, 2, 3, 4, 5, 6, 7);
            oacc = __builtin_amdgcn_mfma_f32_16x16x32_bf16(pa, vfull, oacc, 0, 0, 0);
        }
    }
    #pragma unroll
    for (int r = 0; r < 4; ++r)
        ob[(size_t)(q0 + mba * 16 + quad * 4 + r) * D + kkb * 16 + tq] = oacc[r];
}

extern "C" void kernel_launch(void* const* d_in, const int* in_sizes, int n_in,
                              void* d_out, int out_size, void* d_ws, size_t ws_size,
                              hipStream_t stream) {
    const float* q = (const float*)d_in[0];
    const float* k = (const float*)d_in[1];
    const float* v = (const float*)d_in[2];
    float* out = (float*)d_out;
    const int nbatch = in_sizes[0] / (S * D);   // 4
    const size_t elems = (size_t)nbatch * S * D;

    // ws: kf (fp16, 2MB) | vf (bf16, 2MB) | partial[8] (fp32, 32MB) = 36MB
    const size_t need = elems * 2 * 2 + elems * 8 * 4;
    if (nbatch == 4 && ws_size >= need && d_ws != nullptr) {
        unsigned short* kf = (unsigned short*)d_ws;
        unsigned short* vf = kf + elems;
        float* partial = (float*)(vf + elems);

        prep2<<<nbatch * TILES * 2, 256, 0, stream>>>(k, v, kf, vf);
        attn_main10<<<256, 512, 0, stream>>>(q, kf, vf, partial);
        const int n4 = (int)(elems / 4);
        reduce_out8<<<(n4 + 255) / 256, 256, 0, stream>>>(
            (const float4*)partial, (float4*)out, n4);
    } else {
        dim3 grid(S / 64, nbatch);
        attn_fallback<<<grid, 1024, 0, stream>>>(q, k, v, out);
    }
}